// Round 10
// baseline (479.263 us; speedup 1.0000x reference)
//
#include <hip/hip_runtime.h>

// ProdAttention: LN -> QKV proj -> per-head top-32 of q.k^T (softmax monotone
// => select on raw sim) -> unweighted gather-sum of selected v rows -> global
// minmax-normalize + exp -> transpose -> output proj + bias.
// GEMM-shaped compute on MFMA with f16 hi/lo split (3 terms ~ fp32).
// R10: selection prefilter: per-row T0 = mean + 1.5*sigma (~68 expected
// candidates); exact 2-register binary search over compacted candidates;
// wave-uniform fallback to the full 16-register search when the candidate
// count is outside [32,128] (statistics only affect SPEED, never the set).
// Gather vectorized to dwordx4 + cross-lane reduce.

#define LN_EPS 1e-5f

using half8   = __attribute__((ext_vector_type(8))) _Float16;
using half4   = __attribute__((ext_vector_type(4))) _Float16;
using float4v = __attribute__((ext_vector_type(4))) float;

__device__ __forceinline__ void gload_lds16(const void* g, void* l) {
  __builtin_amdgcn_global_load_lds(
      (const __attribute__((address_space(1))) void*)g,
      (__attribute__((address_space(3))) void*)l, 16, 0, 0);
}
__device__ __forceinline__ float4v mfma16(half8 a, half8 b, float4v c) {
  return __builtin_amdgcn_mfma_f32_16x16x32_f16(a, b, c, 0, 0, 0);
}
struct HL { _Float16 h, l; };
__device__ __forceinline__ HL split2(float x) {
  _Float16 h = (_Float16)x;
  return { h, (_Float16)(x - (float)h) };
}

// ---------------- order-preserving key helpers ----------------
__device__ __forceinline__ unsigned fkey(float f) {
  unsigned u = __float_as_uint(f);
  return ((int)u < 0) ? ~u : (u | 0x80000000u);
}
__device__ __forceinline__ int enc_i(float f) {
  int i = __float_as_int(f);
  return i >= 0 ? i : (i ^ 0x7fffffff);
}
__device__ __forceinline__ float dec_i(int e) {
  return __int_as_float(e >= 0 ? e : (e ^ 0x7fffffff));
}

// ---------------- K1: LayerNorm -> f16 hi/lo planes ----------------
__global__ __launch_bounds__(256)
void ln_kernel(const float* __restrict__ x, const float* __restrict__ gamma,
               const float* __restrict__ beta,
               _Float16* __restrict__ xh, _Float16* __restrict__ xl) {
  __shared__ float red[8];
  int row = blockIdx.x, t = threadIdx.x;
  const float4* xr = (const float4*)(x + (size_t)row * 1024);
  float4 v = xr[t];
  float s  = v.x + v.y + v.z + v.w;
  float s2 = v.x*v.x + v.y*v.y + v.z*v.z + v.w*v.w;
  #pragma unroll
  for (int o = 32; o >= 1; o >>= 1) {
    s  += __shfl_xor(s,  o, 64);
    s2 += __shfl_xor(s2, o, 64);
  }
  int w = t >> 6, l = t & 63;
  if (l == 0) { red[w*2] = s; red[w*2+1] = s2; }
  __syncthreads();
  float S  = red[0] + red[2] + red[4] + red[6];
  float S2 = red[1] + red[3] + red[5] + red[7];
  float mu  = S * (1.0f/1024.0f);
  float var = S2 * (1.0f/1024.0f) - mu*mu;
  float r = rsqrtf(var + LN_EPS);
  float4 g  = ((const float4*)gamma)[t];
  float4 bb = ((const float4*)beta)[t];
  float o0 = (v.x - mu) * r * g.x + bb.x;
  float o1 = (v.y - mu) * r * g.y + bb.y;
  float o2 = (v.z - mu) * r * g.z + bb.z;
  float o3 = (v.w - mu) * r * g.w + bb.w;
  HL r0 = split2(o0), r1 = split2(o1), r2 = split2(o2), r3 = split2(o3);
  half4 hh = { r0.h, r1.h, r2.h, r3.h };
  half4 ll = { r0.l, r1.l, r2.l, r3.l };
  size_t e = (size_t)row * 1024 + t*4;
  *(half4*)(xh + e) = hh;
  *(half4*)(xl + e) = ll;
}

// ---------------- K1b: weight fp32 -> f16 hi/lo planes ----------------
__global__ __launch_bounds__(256)
void cvt_kernel(const float* __restrict__ wqkv, const float* __restrict__ wout,
                _Float16* __restrict__ wqh, _Float16* __restrict__ wql,
                _Float16* __restrict__ woh, _Float16* __restrict__ wol) {
  size_t i4 = (size_t)blockIdx.x * 256 + threadIdx.x;   // float4 index, 1M total
  const float* src; _Float16 *dh, *dl; size_t off;
  if (i4 < 786432) { src = wqkv; dh = wqh; dl = wql; off = i4; }
  else             { src = wout; dh = woh; dl = wol; off = i4 - 786432; }
  float4 v = ((const float4*)src)[off];
  HL r0 = split2(v.x), r1 = split2(v.y), r2 = split2(v.z), r3 = split2(v.w);
  half4 hh = { r0.h, r1.h, r2.h, r3.h };
  half4 ll = { r0.l, r1.l, r2.l, r3.l };
  ((half4*)dh)[off] = hh;
  ((half4*)dl)[off] = ll;
}

// ---------------- K2/K7: f16-split MFMA NT GEMM, 128x128 tile ----------------
template<int MODE>
__global__ __launch_bounds__(256)
void gemm_f16split(const _Float16* __restrict__ Ah, const _Float16* __restrict__ Al,
                   const _Float16* __restrict__ Bh, const _Float16* __restrict__ Bl,
                   const float* __restrict__ bias, float* __restrict__ CO,
                   _Float16* __restrict__ QH, _Float16* __restrict__ QL,
                   _Float16* __restrict__ KH, _Float16* __restrict__ KL,
                   float* __restrict__ CV) {
  __shared__ __align__(16) _Float16 lds[4 * 128 * 32];  // Ah | Al | Bh | Bl tiles
  const int K = 1024;
  int tid = threadIdx.x, w = tid >> 6, l = tid & 63;
  int m0 = blockIdx.y * 128, n0 = blockIdx.x * 128;
  int wm = (w >> 1) * 64, wn = (w & 1) * 64;

  const _Float16* src = (w == 0) ? Ah : (w == 1) ? Al : (w == 2) ? Bh : Bl;
  int rowbase = (w < 2) ? m0 : n0;
  _Float16* dst = lds + (size_t)w * 4096;
  int sr = l >> 2, sc = l & 3;

  float4v acc[4][4];
  #pragma unroll
  for (int u = 0; u < 4; ++u)
    #pragma unroll
    for (int vv = 0; vv < 4; ++vv) acc[u][vv] = (float4v){0.f, 0.f, 0.f, 0.f};

  int quad = l >> 4, lo16 = l & 15;
  for (int kt = 0; kt < K; kt += 32) {
    __syncthreads();
    #pragma unroll
    for (int i = 0; i < 8; ++i) {
      int row = i * 16 + sr;
      gload_lds16(src + (size_t)(rowbase + row) * K + kt + sc * 8,
                  dst + row * 32 + sc * 8);
    }
    __syncthreads();
    half8 ah[4], al[4], bh[4], bl[4];
    #pragma unroll
    for (int u = 0; u < 4; ++u) {
      int mrow = wm + u * 16 + lo16;
      int nrow = wn + u * 16 + lo16;
      ah[u] = *(const half8*)&lds[        (size_t)mrow * 32 + quad * 8];
      al[u] = *(const half8*)&lds[ 4096 + (size_t)mrow * 32 + quad * 8];
      bh[u] = *(const half8*)&lds[ 8192 + (size_t)nrow * 32 + quad * 8];
      bl[u] = *(const half8*)&lds[12288 + (size_t)nrow * 32 + quad * 8];
    }
    #pragma unroll
    for (int u = 0; u < 4; ++u)
      #pragma unroll
      for (int vv = 0; vv < 4; ++vv) {
        acc[u][vv] = mfma16(ah[u], bh[vv], acc[u][vv]);
        acc[u][vv] = mfma16(ah[u], bl[vv], acc[u][vv]);
        acc[u][vv] = mfma16(al[u], bh[vv], acc[u][vv]);
      }
  }

  #pragma unroll
  for (int u = 0; u < 4; ++u) {
    #pragma unroll
    for (int vv = 0; vv < 4; ++vv) {
      #pragma unroll
      for (int rg = 0; rg < 4; ++rg) {
        int row = m0 + wm + u * 16 + quad * 4 + rg;
        int col = n0 + wn + vv * 16 + lo16;
        float val = acc[u][vv][rg];
        if (MODE == 0) {
          int which = col >> 10, h = (col >> 6) & 15, dd = col & 63;
          int b = row >> 10, i = row & 1023;
          size_t e = ((size_t)(b * 16 + h) << 16) + ((size_t)i << 6) + dd;
          if (which == 2) { CV[e] = val; }
          else {
            HL sp = split2(val);
            if (which == 0) { QH[e] = sp.h; QL[e] = sp.l; }
            else            { KH[e] = sp.h; KL[e] = sp.l; }
          }
        } else {
          CO[(size_t)row * 1024 + col] = val + bias[col];
        }
      }
    }
  }
}

// ---------------- K3 init ----------------
__global__ void init_kernel(int* minmax) {
  minmax[0] = 0x7fffffff;
  minmax[1] = (int)0x80000000;
}

// ---------------- K4: fused MFMA sim + top-32 select + v gather-sum ---------
__global__ __launch_bounds__(1024)
void attn_kernel(const _Float16* __restrict__ qh, const _Float16* __restrict__ ql,
                 const _Float16* __restrict__ kh, const _Float16* __restrict__ kl,
                 const float* __restrict__ vg, float* __restrict__ xsum) {
  __shared__ float simb[16][1028];       // stride 1028: writes 2-way max (free)
  __shared__ int sel[16][32];
  __shared__ unsigned short candj[16][128];
  int g = blockIdx.x;
  int xcd = g & 7, slot = g >> 3;
  int bh = (slot >> 6) * 8 + xcd, grp = slot & 63;
  int tid = threadIdx.x, w = tid >> 6, l = tid & 63;
  int quad = l >> 4, lo16 = l & 15;
  size_t hb = (size_t)bh << 16;

  // ---- sim: wave w computes 64-col strip via f16-split MFMA ----
  const _Float16* qhp = qh + hb + ((size_t)(grp * 16 + lo16) << 6);
  const _Float16* qlp = ql + hb + ((size_t)(grp * 16 + lo16) << 6);
  half8 ah0 = *(const half8*)(qhp + quad * 8);
  half8 ah1 = *(const half8*)(qhp + 32 + quad * 8);
  half8 al0 = *(const half8*)(qlp + quad * 8);
  half8 al1 = *(const half8*)(qlp + 32 + quad * 8);

  const _Float16* khp = kh + hb;
  const _Float16* klp = kl + hb;
  int jbase = w * 64;

  #pragma unroll
  for (int tt = 0; tt < 4; ++tt) {
    size_t off = ((size_t)(jbase + tt * 16 + lo16) << 6) + quad * 8;
    half8 b0 = *(const half8*)(khp + off);
    half8 b1 = *(const half8*)(khp + off + 32);
    half8 c0 = *(const half8*)(klp + off);
    half8 c1 = *(const half8*)(klp + off + 32);
    float4v acc = (float4v){0.f, 0.f, 0.f, 0.f};
    acc = mfma16(ah0, b0, acc);
    acc = mfma16(ah0, c0, acc);
    acc = mfma16(al0, b0, acc);
    acc = mfma16(ah1, b1, acc);
    acc = mfma16(ah1, c1, acc);
    acc = mfma16(al1, b1, acc);
    int jc = jbase + tt * 16 + lo16;
    #pragma unroll
    for (int rg = 0; rg < 4; ++rg)
      simb[quad * 4 + rg][jc] = acc[rg];
  }
  __syncthreads();

  // ---- selection: wave w selects row w ----
  unsigned long long below = (1ull << l) - 1ull;
  float s1 = 0.f, s2 = 0.f;
  unsigned ku[16];
  #pragma unroll
  for (int s = 0; s < 16; ++s) {
    float fv = simb[w][s * 64 + l];
    s1 += fv;
    s2 += fv * fv;
    ku[s] = fkey(fv);
  }
  #pragma unroll
  for (int o = 32; o >= 1; o >>= 1) {
    s1 += __shfl_xor(s1, o, 64);
    s2 += __shfl_xor(s2, o, 64);
  }
  float mhat = s1 * (1.0f / 1024.0f);
  float var  = s2 * (1.0f / 1024.0f) - mhat * mhat;
  float T0f  = mhat + 1.5f * sqrtf(fmaxf(var, 0.f));
  unsigned kT0 = fkey(T0f);

  int C0 = 0;
  bool ok = (T0f > 0.f);
  unsigned long long msk[16];
  if (ok) {
    #pragma unroll
    for (int s = 0; s < 16; ++s) {
      msk[s] = __ballot(ku[s] >= kT0);
      C0 += __popcll(msk[s]);
    }
    ok = (C0 >= 32 && C0 <= 128);
  }

  if (ok) {
    // compact candidate indices (ascending j order: s-major, l-minor)
    int A = 0;
    #pragma unroll
    for (int s = 0; s < 16; ++s) {
      bool a = (ku[s] >= kT0);
      int r = A + __popcll(msk[s] & below);
      if (a) candj[w][r] = (unsigned short)(s * 64 + l);
      A += __popcll(msk[s]);
    }
    // load up to 2 candidates per lane (position order == j order)
    unsigned ck0 = 0u, ck1 = 0u;
    int j0 = 0, j1 = 0;
    if (l < A)      { j0 = candj[w][l];      ck0 = fkey(simb[w][j0]); }
    if (64 + l < A) { j1 = candj[w][64 + l]; ck1 = fkey(simb[w][j1]); }

    unsigned cur; int need;
    if (C0 == 32) {
      cur = kT0; need = 9999;            // take all candidates
    } else {
      cur = 0u; bool exact = false;
      for (int bit = 31; bit >= 0; --bit) {
        unsigned T = cur | (1u << bit);
        if (T <= kT0) { cur = T; continue; }     // count >= C0 >= 32 (SALU skip)
        int c = __popcll(__ballot(ck0 >= T)) + __popcll(__ballot(ck1 >= T));
        if (c >= 32) {
          cur = T;
          if (c == 32) { exact = true; break; }
        }
      }
      if (exact) need = 9999;
      else {
        int gcnt = __popcll(__ballot(ck0 > cur)) + __popcll(__ballot(ck1 > cur));
        need = 32 - gcnt;                // ties lowest-j first (jax tie-break)
      }
    }
    // take-pass over the 2 candidate registers (j-ascending ballot order)
    int base = 0, eqb = 0;
    {
      bool gt = ck0 > cur, eq = ck0 == cur;
      unsigned long long meq = __ballot(eq);
      int eqr = eqb + __popcll(meq & below);
      bool take = gt || (eq && (eqr < need));
      unsigned long long mtk = __ballot(take);
      if (take) sel[w][base + __popcll(mtk & below)] = j0;
      base += __popcll(mtk);
      eqb  += __popcll(meq);
    }
    {
      bool gt = ck1 > cur, eq = ck1 == cur;
      unsigned long long meq = __ballot(eq);
      int eqr = eqb + __popcll(meq & below);
      bool take = gt || (eq && (eqr < need));
      unsigned long long mtk = __ballot(take);
      if (take) sel[w][base + __popcll(mtk & below)] = j1;
      base += __popcll(mtk);
      eqb  += __popcll(meq);
    }
  } else {
    // ---- exact fallback: full 16-register binary search (rare) ----
    unsigned cur = 0u; bool exact = false;
    for (int bit = 31; bit >= 0; --bit) {
      unsigned T = cur | (1u << bit);
      int c = 0;
      #pragma unroll
      for (int s = 0; s < 16; ++s) c += __popcll(__ballot(ku[s] >= T));
      if (c >= 32) {
        cur = T;
        if (c == 32) { exact = true; break; }
      }
    }
    int need = 9999;
    if (!exact) {
      int gcnt = 0;
      #pragma unroll
      for (int s = 0; s < 16; ++s) gcnt += __popcll(__ballot(ku[s] > cur));
      need = 32 - gcnt;
    }
    int base = 0, eqb = 0;
    #pragma unroll
    for (int s = 0; s < 16; ++s) {
      bool gt = ku[s] > cur;
      bool eq = ku[s] == cur;
      unsigned long long meq = __ballot(eq);
      int eqr = eqb + __popcll(meq & below);
      bool take = gt || (eq && (eqr < need));
      unsigned long long mtk = __ballot(take);
      if (take) sel[w][base + __popcll(mtk & below)] = s * 64 + l;
      base += __popcll(mtk);
      eqb  += __popcll(meq);
    }
  }

  // ---- gather: 8 dwordx4 loads + cross-lane reduce (sum of 32 v rows) ----
  const float* vb = vg + hb;
  float4 vacc = {0.f, 0.f, 0.f, 0.f};
  #pragma unroll
  for (int p = 0; p < 8; ++p) {
    int j = sel[w][p * 4 + (l >> 4)];
    float4 t = *(const float4*)(vb + ((size_t)j << 6) + (l & 15) * 4);
    vacc.x += t.x; vacc.y += t.y; vacc.z += t.z; vacc.w += t.w;
  }
  #pragma unroll
  for (int o = 32; o >= 16; o >>= 1) {
    vacc.x += __shfl_xor(vacc.x, o, 64);
    vacc.y += __shfl_xor(vacc.y, o, 64);
    vacc.z += __shfl_xor(vacc.z, o, 64);
    vacc.w += __shfl_xor(vacc.w, o, 64);
  }
  if (l < 16)
    *(float4*)(xsum + hb + ((size_t)(grp * 16 + w) << 6) + l * 4) = vacc;
}

// ---------------- K5: global min/max reduce over xsum (256 blocks) ----------
__global__ __launch_bounds__(256)
void reduce_kernel(const float* __restrict__ xsum, int* __restrict__ minmax) {
  __shared__ float red[8];
  int tid = threadIdx.x, w = tid >> 6, l = tid & 63;
  const float4* p = (const float4*)xsum + (size_t)blockIdx.x * 4096 + tid;
  float mn = 3.4e38f, mx = -3.4e38f;
  #pragma unroll
  for (int i = 0; i < 16; ++i) {
    float4 v = p[(size_t)i * 256];
    mn = fminf(mn, fminf(fminf(v.x, v.y), fminf(v.z, v.w)));
    mx = fmaxf(mx, fmaxf(fmaxf(v.x, v.y), fmaxf(v.z, v.w)));
  }
  #pragma unroll
  for (int o = 32; o >= 1; o >>= 1) {
    mn = fminf(mn, __shfl_xor(mn, o, 64));
    mx = fmaxf(mx, __shfl_xor(mx, o, 64));
  }
  if (l == 0) { red[w*2] = mn; red[w*2+1] = mx; }
  __syncthreads();
  if (tid == 0) {
    mn = fminf(fminf(red[0], red[2]), fminf(red[4], red[6]));
    mx = fmaxf(fmaxf(red[1], red[3]), fmaxf(red[5], red[7]));
    atomicMin(minmax,     enc_i(mn));
    atomicMax(minmax + 1, enc_i(mx));
  }
}

// ---------------- K6: minmax-norm + exp + transpose -> f16 hi/lo ------------
__global__ __launch_bounds__(256)
void fin_kernel(const float* __restrict__ xsum, const int* __restrict__ minmax,
                _Float16* __restrict__ oh, _Float16* __restrict__ ol) {
  int idx = blockIdx.x * 256 + threadIdx.x;  // float4 index
  float mn = dec_i(minmax[0]);
  float mx = dec_i(minmax[1]);
  float inv = 1.0f / (mx - mn);
  float4 xv = ((const float4*)xsum)[idx];
  float o0 = expf((xv.x - mn) * inv);
  float o1 = expf((xv.y - mn) * inv);
  float o2 = expf((xv.z - mn) * inv);
  float o3 = expf((xv.w - mn) * inv);
  HL r0 = split2(o0), r1 = split2(o1), r2 = split2(o2), r3 = split2(o3);
  half4 hh = { r0.h, r1.h, r2.h, r3.h };
  half4 ll = { r0.l, r1.l, r2.l, r3.l };
  int e0 = idx << 2;
  int bh = e0 >> 16, i = (e0 >> 6) & 1023, dd = e0 & 63;
  int b = bh >> 4, h = bh & 15;
  size_t oe = ((size_t)(b * 1024 + i) << 10) + (h << 6) + dd;
  *(half4*)(oh + oe) = hh;
  *(half4*)(ol + oe) = ll;
}

// ---------------- launch ----------------
extern "C" void kernel_launch(void* const* d_in, const int* in_sizes, int n_in,
                              void* d_out, int out_size, void* d_ws, size_t ws_size,
                              hipStream_t stream) {
  const float* x     = (const float*)d_in[0];
  const float* gamma = (const float*)d_in[1];
  const float* beta  = (const float*)d_in[2];
  const float* w_qkv = (const float*)d_in[3];
  const float* w_out = (const float*)d_in[4];
  const float* b_out = (const float*)d_in[5];

  char* B = (char*)d_ws;
  const size_t MB = 1024ull * 1024ull;
  float*    v   = (float*)B;                        // 16 MB [bh][n][d]
  _Float16* qh  = (_Float16*)(B + 16*MB);           // 8 MB each plane
  _Float16* ql  = (_Float16*)(B + 24*MB);
  _Float16* kh  = (_Float16*)(B + 32*MB);
  _Float16* kl  = (_Float16*)(B + 40*MB);
  float*    xs  = (float*)(B + 48*MB);              // 16 MB (attn output)
  _Float16* xh  = (_Float16*)(B + 48*MB);           // LN planes (dead before xs)
  _Float16* xl  = (_Float16*)(B + 56*MB);
  _Float16* woh = (_Float16*)(B + 64*MB);           // 2 MB each
  _Float16* wol = (_Float16*)(B + 66*MB);
  int*   minmax = (int*)(B + 68*MB);
  _Float16* wqh = (_Float16*)(B + 69*MB);           // 6 MB each
  _Float16* wql = (_Float16*)(B + 75*MB);
  _Float16* oth = qh;                               // reuse q planes after attn
  _Float16* otl = ql;

  ln_kernel<<<4096, 256, 0, stream>>>(x, gamma, beta, xh, xl);
  cvt_kernel<<<4096, 256, 0, stream>>>(w_qkv, w_out, wqh, wql, woh, wol);
  gemm_f16split<0><<<dim3(24, 32), 256, 0, stream>>>(
      xh, xl, wqh, wql, nullptr, nullptr, qh, ql, kh, kl, v);
  init_kernel<<<1, 1, 0, stream>>>(minmax);
  attn_kernel<<<4096, 1024, 0, stream>>>(qh, ql, kh, kl, v, xs);
  reduce_kernel<<<256, 256, 0, stream>>>(xs, minmax);
  fin_kernel<<<4096, 256, 0, stream>>>(xs, minmax, oth, otl);
  gemm_f16split<1><<<dim3(8, 32), 256, 0, stream>>>(
      oth, otl, woh, wol, b_out, (float*)d_out,
      nullptr, nullptr, nullptr, nullptr, nullptr);
}

// Round 11
// 417.305 us; speedup vs baseline: 1.1485x; 1.1485x over previous
//
#include <hip/hip_runtime.h>

// ProdAttention: LN -> QKV proj -> per-head top-32 of q.k^T (softmax monotone
// => select on raw sim) -> unweighted gather-sum of selected v rows -> global
// minmax-normalize + exp -> transpose -> output proj + bias.
// GEMM-shaped compute on MFMA with f16 hi/lo split (3 terms ~ fp32).
// R11: attn reverted to R9 (R10's prefilter added serial latency chains ->
// regression).  gemm1 now 128x64 tiles (2 blocks/CU, was 1).  ln+cvt merged.

#define LN_EPS 1e-5f

using half8   = __attribute__((ext_vector_type(8))) _Float16;
using half4   = __attribute__((ext_vector_type(4))) _Float16;
using float4v = __attribute__((ext_vector_type(4))) float;

__device__ __forceinline__ void gload_lds16(const void* g, void* l) {
  __builtin_amdgcn_global_load_lds(
      (const __attribute__((address_space(1))) void*)g,
      (__attribute__((address_space(3))) void*)l, 16, 0, 0);
}
__device__ __forceinline__ float4v mfma16(half8 a, half8 b, float4v c) {
  return __builtin_amdgcn_mfma_f32_16x16x32_f16(a, b, c, 0, 0, 0);
}
struct HL { _Float16 h, l; };
__device__ __forceinline__ HL split2(float x) {
  _Float16 h = (_Float16)x;
  return { h, (_Float16)(x - (float)h) };
}

// ---------------- order-preserving key helpers ----------------
__device__ __forceinline__ unsigned fkey(float f) {
  unsigned u = __float_as_uint(f);
  return ((int)u < 0) ? ~u : (u | 0x80000000u);
}
__device__ __forceinline__ int enc_i(float f) {
  int i = __float_as_int(f);
  return i >= 0 ? i : (i ^ 0x7fffffff);
}
__device__ __forceinline__ float dec_i(int e) {
  return __int_as_float(e >= 0 ? e : (e ^ 0x7fffffff));
}

// ---------------- K1: fused LayerNorm + weight-convert -> f16 hi/lo ---------
// blocks 0..4095: LN row; blocks 4096..8191: weight cvt chunk.
__global__ __launch_bounds__(256)
void prep_kernel(const float* __restrict__ x, const float* __restrict__ gamma,
                 const float* __restrict__ beta,
                 _Float16* __restrict__ xh, _Float16* __restrict__ xl,
                 const float* __restrict__ wqkv, const float* __restrict__ wout,
                 _Float16* __restrict__ wqh, _Float16* __restrict__ wql,
                 _Float16* __restrict__ woh, _Float16* __restrict__ wol) {
  int blk = blockIdx.x, t = threadIdx.x;
  if (blk < 4096) {
    __shared__ float red[8];
    int row = blk;
    const float4* xr = (const float4*)(x + (size_t)row * 1024);
    float4 v = xr[t];
    float s  = v.x + v.y + v.z + v.w;
    float s2 = v.x*v.x + v.y*v.y + v.z*v.z + v.w*v.w;
    #pragma unroll
    for (int o = 32; o >= 1; o >>= 1) {
      s  += __shfl_xor(s,  o, 64);
      s2 += __shfl_xor(s2, o, 64);
    }
    int w = t >> 6, l = t & 63;
    if (l == 0) { red[w*2] = s; red[w*2+1] = s2; }
    __syncthreads();
    float S  = red[0] + red[2] + red[4] + red[6];
    float S2 = red[1] + red[3] + red[5] + red[7];
    float mu  = S * (1.0f/1024.0f);
    float var = S2 * (1.0f/1024.0f) - mu*mu;
    float r = rsqrtf(var + LN_EPS);
    float4 g  = ((const float4*)gamma)[t];
    float4 bb = ((const float4*)beta)[t];
    float o0 = (v.x - mu) * r * g.x + bb.x;
    float o1 = (v.y - mu) * r * g.y + bb.y;
    float o2 = (v.z - mu) * r * g.z + bb.z;
    float o3 = (v.w - mu) * r * g.w + bb.w;
    HL r0 = split2(o0), r1 = split2(o1), r2 = split2(o2), r3 = split2(o3);
    half4 hh = { r0.h, r1.h, r2.h, r3.h };
    half4 ll = { r0.l, r1.l, r2.l, r3.l };
    size_t e = (size_t)row * 1024 + t*4;
    *(half4*)(xh + e) = hh;
    *(half4*)(xl + e) = ll;
  } else {
    size_t i4 = (size_t)(blk - 4096) * 256 + t;   // float4 index, 1M total
    const float* src; _Float16 *dh, *dl; size_t off;
    if (i4 < 786432) { src = wqkv; dh = wqh; dl = wql; off = i4; }
    else             { src = wout; dh = woh; dl = wol; off = i4 - 786432; }
    float4 v = ((const float4*)src)[off];
    HL r0 = split2(v.x), r1 = split2(v.y), r2 = split2(v.z), r3 = split2(v.w);
    half4 hh = { r0.h, r1.h, r2.h, r3.h };
    half4 ll = { r0.l, r1.l, r2.l, r3.l };
    ((half4*)dh)[off] = hh;
    ((half4*)dl)[off] = ll;
  }
}

// ---------------- K2/K7: f16-split MFMA NT GEMM, 128xNT tile ----------------
// C[m][n] = sum_k A[m][k]*B[n][k], A = Ah+Al, B = Bh+Bl (3 MFMA terms).
// MODE 0 (NT=128): scatter q,k -> f16 hi/lo planes [bh][n][d]; v fp32.
// MODE 1 (NT=64):  CO = acc + bias (fp32); 2 blocks/CU for latency hiding.
template<int MODE, int NT>
__global__ __launch_bounds__(256)
void gemm_f16split(const _Float16* __restrict__ Ah, const _Float16* __restrict__ Al,
                   const _Float16* __restrict__ Bh, const _Float16* __restrict__ Bl,
                   const float* __restrict__ bias, float* __restrict__ CO,
                   _Float16* __restrict__ QH, _Float16* __restrict__ QL,
                   _Float16* __restrict__ KH, _Float16* __restrict__ KL,
                   float* __restrict__ CV) {
  constexpr int NV = NT / 32;                     // n-tiles per wave
  __shared__ __align__(16) _Float16 lds[8192 + 2 * NT * 32];  // Ah|Al|Bh|Bl
  const int K = 1024;
  int tid = threadIdx.x, w = tid >> 6, l = tid & 63;
  int m0 = blockIdx.y * 128, n0 = blockIdx.x * NT;
  int wm = (w >> 1) * 64, wn = (w & 1) * (NT / 2);

  const _Float16* src = (w == 0) ? Ah : (w == 1) ? Al : (w == 2) ? Bh : Bl;
  int rowbase = (w < 2) ? m0 : n0;
  int iters   = (w < 2) ? 8 : NT / 16;
  _Float16* dst = lds + ((w < 2) ? (size_t)w * 4096
                                 : (size_t)8192 + (size_t)(w - 2) * NT * 32);
  int sr = l >> 2, sc = l & 3;

  float4v acc[4][NV];
  #pragma unroll
  for (int u = 0; u < 4; ++u)
    #pragma unroll
    for (int vv = 0; vv < NV; ++vv) acc[u][vv] = (float4v){0.f, 0.f, 0.f, 0.f};

  int quad = l >> 4, lo16 = l & 15;
  for (int kt = 0; kt < K; kt += 32) {
    __syncthreads();
    for (int i = 0; i < iters; ++i) {
      int row = i * 16 + sr;
      gload_lds16(src + (size_t)(rowbase + row) * K + kt + sc * 8,
                  dst + row * 32 + sc * 8);
    }
    __syncthreads();
    half8 ah[4], al[4], bh[NV], bl[NV];
    #pragma unroll
    for (int u = 0; u < 4; ++u) {
      int mrow = wm + u * 16 + lo16;
      ah[u] = *(const half8*)&lds[        (size_t)mrow * 32 + quad * 8];
      al[u] = *(const half8*)&lds[ 4096 + (size_t)mrow * 32 + quad * 8];
    }
    #pragma unroll
    for (int vv = 0; vv < NV; ++vv) {
      int nrow = wn + vv * 16 + lo16;
      bh[vv] = *(const half8*)&lds[8192           + (size_t)nrow * 32 + quad * 8];
      bl[vv] = *(const half8*)&lds[8192 + NT * 32 + (size_t)nrow * 32 + quad * 8];
    }
    #pragma unroll
    for (int u = 0; u < 4; ++u)
      #pragma unroll
      for (int vv = 0; vv < NV; ++vv) {
        acc[u][vv] = mfma16(ah[u], bh[vv], acc[u][vv]);
        acc[u][vv] = mfma16(ah[u], bl[vv], acc[u][vv]);
        acc[u][vv] = mfma16(al[u], bh[vv], acc[u][vv]);
      }
  }

  // epilogue: C row = m ((lane>>4)*4+reg), col = n (lane&15)
  #pragma unroll
  for (int u = 0; u < 4; ++u) {
    #pragma unroll
    for (int vv = 0; vv < NV; ++vv) {
      #pragma unroll
      for (int rg = 0; rg < 4; ++rg) {
        int row = m0 + wm + u * 16 + quad * 4 + rg;
        int col = n0 + wn + vv * 16 + lo16;
        float val = acc[u][vv][rg];
        if (MODE == 0) {
          int which = col >> 10, h = (col >> 6) & 15, dd = col & 63;
          int b = row >> 10, i = row & 1023;
          size_t e = ((size_t)(b * 16 + h) << 16) + ((size_t)i << 6) + dd;
          if (which == 2) { CV[e] = val; }
          else {
            HL sp = split2(val);
            if (which == 0) { QH[e] = sp.h; QL[e] = sp.l; }
            else            { KH[e] = sp.h; KL[e] = sp.l; }
          }
        } else {
          CO[(size_t)row * 1024 + col] = val + bias[col];
        }
      }
    }
  }
}

// ---------------- K3 init ----------------
__global__ void init_kernel(int* minmax) {
  minmax[0] = 0x7fffffff;
  minmax[1] = (int)0x80000000;
}

// ---------------- K4: fused MFMA sim + top-32 select + v gather-sum ---------
// (R9 structure: 1024-thread blocks, 16 waves share 66KB sim LDS ->
//  2 blocks/CU = 32 waves/CU.  Wave w: 64-col MFMA strip, then selects row w.)
__global__ __launch_bounds__(1024)
void attn_kernel(const _Float16* __restrict__ qh, const _Float16* __restrict__ ql,
                 const _Float16* __restrict__ kh, const _Float16* __restrict__ kl,
                 const float* __restrict__ vg, float* __restrict__ xsum) {
  __shared__ float simb[16][1028];   // stride 1028: writes land 2-way max (free)
  __shared__ int sel[16][32];
  // XCD swizzle: all 64 row-blocks of a head on one XCD (k planes fit L2)
  int g = blockIdx.x;
  int xcd = g & 7, slot = g >> 3;
  int bh = (slot >> 6) * 8 + xcd, grp = slot & 63;
  int tid = threadIdx.x, w = tid >> 6, l = tid & 63;
  int quad = l >> 4, lo16 = l & 15;
  size_t hb = (size_t)bh << 16;

  // A-frags: q rows grp*16..+15 (same for all 16 waves; L1 broadcast)
  const _Float16* qhp = qh + hb + ((size_t)(grp * 16 + lo16) << 6);
  const _Float16* qlp = ql + hb + ((size_t)(grp * 16 + lo16) << 6);
  half8 ah0 = *(const half8*)(qhp + quad * 8);
  half8 ah1 = *(const half8*)(qhp + 32 + quad * 8);
  half8 al0 = *(const half8*)(qlp + quad * 8);
  half8 al1 = *(const half8*)(qlp + 32 + quad * 8);

  const _Float16* khp = kh + hb;
  const _Float16* klp = kl + hb;
  int jbase = w * 64;

  #pragma unroll
  for (int tt = 0; tt < 4; ++tt) {
    size_t off = ((size_t)(jbase + tt * 16 + lo16) << 6) + quad * 8;
    half8 b0 = *(const half8*)(khp + off);
    half8 b1 = *(const half8*)(khp + off + 32);
    half8 c0 = *(const half8*)(klp + off);
    half8 c1 = *(const half8*)(klp + off + 32);
    float4v acc = (float4v){0.f, 0.f, 0.f, 0.f};
    acc = mfma16(ah0, b0, acc);
    acc = mfma16(ah0, c0, acc);
    acc = mfma16(al0, b0, acc);
    acc = mfma16(ah1, b1, acc);
    acc = mfma16(ah1, c1, acc);
    acc = mfma16(al1, b1, acc);
    int jc = jbase + tt * 16 + lo16;
    #pragma unroll
    for (int rg = 0; rg < 4; ++rg)
      simb[quad * 4 + rg][jc] = acc[rg];
  }
  __syncthreads();

  // wave w selects row w
  unsigned long long below = (1ull << l) - 1ull;
  unsigned ku[16];
  #pragma unroll
  for (int s = 0; s < 16; ++s) ku[s] = fkey(simb[w][s * 64 + l]);

  // binary search for 32nd-largest key; early exit at exact count 32
  unsigned cur = 0u;
  bool exact = false;
  for (int bit = 31; bit >= 0; --bit) {
    unsigned T = cur | (1u << bit);
    int c = 0;
    #pragma unroll
    for (int s = 0; s < 16; ++s) c += __popcll(__ballot(ku[s] >= T));
    if (c >= 32) {
      cur = T;
      if (c == 32) { exact = true; break; }
    }
  }
  int need = 9999;
  if (!exact) {
    int gcnt = 0;
    #pragma unroll
    for (int s = 0; s < 16; ++s) gcnt += __popcll(__ballot(ku[s] > cur));
    need = 32 - gcnt;   // ties taken lowest-j first (jax tie-break)
  }

  int base = 0, eqb = 0;
  #pragma unroll
  for (int s = 0; s < 16; ++s) {
    bool gt = ku[s] > cur;
    bool eq = ku[s] == cur;
    unsigned long long meq = __ballot(eq);
    int eqr = eqb + __popcll(meq & below);
    bool take = gt || (eq && (eqr < need));
    unsigned long long mtk = __ballot(take);
    if (take) sel[w][base + __popcll(mtk & below)] = s * 64 + l;
    base += __popcll(mtk);
    eqb  += __popcll(meq);
  }

  const float* vb = vg + hb;
  float acc = 0.0f;
  #pragma unroll
  for (int s2 = 0; s2 < 32; ++s2) {
    int j = sel[w][s2];
    acc += vb[((size_t)j << 6) + l];
  }
  xsum[hb + ((size_t)(grp * 16 + w) << 6) + l] = acc;
}

// ---------------- K5: global min/max reduce over xsum (256 blocks) ----------
__global__ __launch_bounds__(256)
void reduce_kernel(const float* __restrict__ xsum, int* __restrict__ minmax) {
  __shared__ float red[8];
  int tid = threadIdx.x, w = tid >> 6, l = tid & 63;
  const float4* p = (const float4*)xsum + (size_t)blockIdx.x * 4096 + tid;
  float mn = 3.4e38f, mx = -3.4e38f;
  #pragma unroll
  for (int i = 0; i < 16; ++i) {
    float4 v = p[(size_t)i * 256];
    mn = fminf(mn, fminf(fminf(v.x, v.y), fminf(v.z, v.w)));
    mx = fmaxf(mx, fmaxf(fmaxf(v.x, v.y), fmaxf(v.z, v.w)));
  }
  #pragma unroll
  for (int o = 32; o >= 1; o >>= 1) {
    mn = fminf(mn, __shfl_xor(mn, o, 64));
    mx = fmaxf(mx, __shfl_xor(mx, o, 64));
  }
  if (l == 0) { red[w*2] = mn; red[w*2+1] = mx; }
  __syncthreads();
  if (tid == 0) {
    mn = fminf(fminf(red[0], red[2]), fminf(red[4], red[6]));
    mx = fmaxf(fmaxf(red[1], red[3]), fmaxf(red[5], red[7]));
    atomicMin(minmax,     enc_i(mn));
    atomicMax(minmax + 1, enc_i(mx));
  }
}

// ---------------- K6: minmax-norm + exp + transpose -> f16 hi/lo ------------
__global__ __launch_bounds__(256)
void fin_kernel(const float* __restrict__ xsum, const int* __restrict__ minmax,
                _Float16* __restrict__ oh, _Float16* __restrict__ ol) {
  int idx = blockIdx.x * 256 + threadIdx.x;  // float4 index
  float mn = dec_i(minmax[0]);
  float mx = dec_i(minmax[1]);
  float inv = 1.0f / (mx - mn);
  float4 xv = ((const float4*)xsum)[idx];
  float o0 = expf((xv.x - mn) * inv);
  float o1 = expf((xv.y - mn) * inv);
  float o2 = expf((xv.z - mn) * inv);
  float o3 = expf((xv.w - mn) * inv);
  HL r0 = split2(o0), r1 = split2(o1), r2 = split2(o2), r3 = split2(o3);
  half4 hh = { r0.h, r1.h, r2.h, r3.h };
  half4 ll = { r0.l, r1.l, r2.l, r3.l };
  int e0 = idx << 2;
  int bh = e0 >> 16, i = (e0 >> 6) & 1023, dd = e0 & 63;
  int b = bh >> 4, h = bh & 15;
  size_t oe = ((size_t)(b * 1024 + i) << 10) + (h << 6) + dd;
  *(half4*)(oh + oe) = hh;
  *(half4*)(ol + oe) = ll;
}

// ---------------- launch ----------------
extern "C" void kernel_launch(void* const* d_in, const int* in_sizes, int n_in,
                              void* d_out, int out_size, void* d_ws, size_t ws_size,
                              hipStream_t stream) {
  const float* x     = (const float*)d_in[0];
  const float* gamma = (const float*)d_in[1];
  const float* beta  = (const float*)d_in[2];
  const float* w_qkv = (const float*)d_in[3];
  const float* w_out = (const float*)d_in[4];
  const float* b_out = (const float*)d_in[5];

  char* B = (char*)d_ws;
  const size_t MB = 1024ull * 1024ull;
  float*    v   = (float*)B;                        // 16 MB [bh][n][d]
  _Float16* qh  = (_Float16*)(B + 16*MB);           // 8 MB each plane
  _Float16* ql  = (_Float16*)(B + 24*MB);
  _Float16* kh  = (_Float16*)(B + 32*MB);
  _Float16* kl  = (_Float16*)(B + 40*MB);
  float*    xs  = (float*)(B + 48*MB);              // 16 MB (attn output)
  _Float16* xh  = (_Float16*)(B + 48*MB);           // LN planes (dead before xs)
  _Float16* xl  = (_Float16*)(B + 56*MB);
  _Float16* woh = (_Float16*)(B + 64*MB);           // 2 MB each
  _Float16* wol = (_Float16*)(B + 66*MB);
  int*   minmax = (int*)(B + 68*MB);
  _Float16* wqh = (_Float16*)(B + 69*MB);           // 6 MB each
  _Float16* wql = (_Float16*)(B + 75*MB);
  _Float16* oth = qh;                               // reuse q planes after attn
  _Float16* otl = ql;

  prep_kernel<<<8192, 256, 0, stream>>>(x, gamma, beta, xh, xl,
                                        w_qkv, w_out, wqh, wql, woh, wol);
  gemm_f16split<0, 128><<<dim3(24, 32), 256, 0, stream>>>(
      xh, xl, wqh, wql, nullptr, nullptr, qh, ql, kh, kl, v);
  init_kernel<<<1, 1, 0, stream>>>(minmax);
  attn_kernel<<<4096, 1024, 0, stream>>>(qh, ql, kh, kl, v, xs);
  reduce_kernel<<<256, 256, 0, stream>>>(xs, minmax);
  fin_kernel<<<4096, 256, 0, stream>>>(xs, minmax, oth, otl);
  gemm_f16split<1, 64><<<dim3(16, 32), 256, 0, stream>>>(
      oth, otl, woh, wol, b_out, (float*)d_out,
      nullptr, nullptr, nullptr, nullptr, nullptr);
}

// Round 12
// 415.619 us; speedup vs baseline: 1.1531x; 1.0041x over previous
//
#include <hip/hip_runtime.h>

// ProdAttention: LN -> QKV proj -> per-head top-32 of q.k^T (softmax monotone
// => select on raw sim) -> unweighted gather-sum of selected v rows -> global
// minmax-normalize + exp -> transpose -> output proj + bias.
// GEMM-shaped compute on MFMA with f16 hi/lo split (3 terms ~ fp32).
// R12: attn take-pass uses v_mbcnt (2-op lane-rank) + wave-uniform exact
// fast path (the binary search exits "exact" unless k32==k33 bit-exactly);
// init fused into prep.  Structure otherwise R11 (known-good).

#define LN_EPS 1e-5f

using half8   = __attribute__((ext_vector_type(8))) _Float16;
using half4   = __attribute__((ext_vector_type(4))) _Float16;
using float4v = __attribute__((ext_vector_type(4))) float;

__device__ __forceinline__ void gload_lds16(const void* g, void* l) {
  __builtin_amdgcn_global_load_lds(
      (const __attribute__((address_space(1))) void*)g,
      (__attribute__((address_space(3))) void*)l, 16, 0, 0);
}
__device__ __forceinline__ float4v mfma16(half8 a, half8 b, float4v c) {
  return __builtin_amdgcn_mfma_f32_16x16x32_f16(a, b, c, 0, 0, 0);
}
struct HL { _Float16 h, l; };
__device__ __forceinline__ HL split2(float x) {
  _Float16 h = (_Float16)x;
  return { h, (_Float16)(x - (float)h) };
}
// rank of this lane within mask (count of set bits strictly below my lane)
__device__ __forceinline__ int mbcnt(unsigned long long m) {
  return __builtin_amdgcn_mbcnt_hi((unsigned)(m >> 32),
         __builtin_amdgcn_mbcnt_lo((unsigned)m, 0u));
}

// ---------------- order-preserving key helpers ----------------
__device__ __forceinline__ unsigned fkey(float f) {
  unsigned u = __float_as_uint(f);
  return ((int)u < 0) ? ~u : (u | 0x80000000u);
}
__device__ __forceinline__ int enc_i(float f) {
  int i = __float_as_int(f);
  return i >= 0 ? i : (i ^ 0x7fffffff);
}
__device__ __forceinline__ float dec_i(int e) {
  return __int_as_float(e >= 0 ? e : (e ^ 0x7fffffff));
}

// ---------------- K1: LN + weight-convert + minmax-init (fused) -------------
// blocks 0..4095: LN row; 4096..8191: weight cvt chunk; 8192: minmax init.
__global__ __launch_bounds__(256)
void prep_kernel(const float* __restrict__ x, const float* __restrict__ gamma,
                 const float* __restrict__ beta,
                 _Float16* __restrict__ xh, _Float16* __restrict__ xl,
                 const float* __restrict__ wqkv, const float* __restrict__ wout,
                 _Float16* __restrict__ wqh, _Float16* __restrict__ wql,
                 _Float16* __restrict__ woh, _Float16* __restrict__ wol,
                 int* __restrict__ minmax) {
  int blk = blockIdx.x, t = threadIdx.x;
  if (blk < 4096) {
    __shared__ float red[8];
    int row = blk;
    const float4* xr = (const float4*)(x + (size_t)row * 1024);
    float4 v = xr[t];
    float s  = v.x + v.y + v.z + v.w;
    float s2 = v.x*v.x + v.y*v.y + v.z*v.z + v.w*v.w;
    #pragma unroll
    for (int o = 32; o >= 1; o >>= 1) {
      s  += __shfl_xor(s,  o, 64);
      s2 += __shfl_xor(s2, o, 64);
    }
    int w = t >> 6, l = t & 63;
    if (l == 0) { red[w*2] = s; red[w*2+1] = s2; }
    __syncthreads();
    float S  = red[0] + red[2] + red[4] + red[6];
    float S2 = red[1] + red[3] + red[5] + red[7];
    float mu  = S * (1.0f/1024.0f);
    float var = S2 * (1.0f/1024.0f) - mu*mu;
    float r = rsqrtf(var + LN_EPS);
    float4 g  = ((const float4*)gamma)[t];
    float4 bb = ((const float4*)beta)[t];
    float o0 = (v.x - mu) * r * g.x + bb.x;
    float o1 = (v.y - mu) * r * g.y + bb.y;
    float o2 = (v.z - mu) * r * g.z + bb.z;
    float o3 = (v.w - mu) * r * g.w + bb.w;
    HL r0 = split2(o0), r1 = split2(o1), r2 = split2(o2), r3 = split2(o3);
    half4 hh = { r0.h, r1.h, r2.h, r3.h };
    half4 ll = { r0.l, r1.l, r2.l, r3.l };
    size_t e = (size_t)row * 1024 + t*4;
    *(half4*)(xh + e) = hh;
    *(half4*)(xl + e) = ll;
  } else if (blk < 8192) {
    size_t i4 = (size_t)(blk - 4096) * 256 + t;   // float4 index, 1M total
    const float* src; _Float16 *dh, *dl; size_t off;
    if (i4 < 786432) { src = wqkv; dh = wqh; dl = wql; off = i4; }
    else             { src = wout; dh = woh; dl = wol; off = i4 - 786432; }
    float4 v = ((const float4*)src)[off];
    HL r0 = split2(v.x), r1 = split2(v.y), r2 = split2(v.z), r3 = split2(v.w);
    half4 hh = { r0.h, r1.h, r2.h, r3.h };
    half4 ll = { r0.l, r1.l, r2.l, r3.l };
    ((half4*)dh)[off] = hh;
    ((half4*)dl)[off] = ll;
  } else if (t == 0) {
    minmax[0] = 0x7fffffff;
    minmax[1] = (int)0x80000000;
  }
}

// ---------------- K2/K6: f16-split MFMA NT GEMM, 128xNT tile ----------------
// C[m][n] = sum_k A[m][k]*B[n][k], A = Ah+Al, B = Bh+Bl (3 MFMA terms).
// MODE 0 (NT=128): scatter q,k -> f16 hi/lo planes [bh][n][d]; v fp32.
// MODE 1 (NT=64):  CO = acc + bias (fp32); 2 blocks/CU for latency hiding.
template<int MODE, int NT>
__global__ __launch_bounds__(256)
void gemm_f16split(const _Float16* __restrict__ Ah, const _Float16* __restrict__ Al,
                   const _Float16* __restrict__ Bh, const _Float16* __restrict__ Bl,
                   const float* __restrict__ bias, float* __restrict__ CO,
                   _Float16* __restrict__ QH, _Float16* __restrict__ QL,
                   _Float16* __restrict__ KH, _Float16* __restrict__ KL,
                   float* __restrict__ CV) {
  constexpr int NV = NT / 32;                     // n-tiles per wave
  __shared__ __align__(16) _Float16 lds[8192 + 2 * NT * 32];  // Ah|Al|Bh|Bl
  const int K = 1024;
  int tid = threadIdx.x, w = tid >> 6, l = tid & 63;
  int m0 = blockIdx.y * 128, n0 = blockIdx.x * NT;
  int wm = (w >> 1) * 64, wn = (w & 1) * (NT / 2);

  const _Float16* src = (w == 0) ? Ah : (w == 1) ? Al : (w == 2) ? Bh : Bl;
  int rowbase = (w < 2) ? m0 : n0;
  int iters   = (w < 2) ? 8 : NT / 16;
  _Float16* dst = lds + ((w < 2) ? (size_t)w * 4096
                                 : (size_t)8192 + (size_t)(w - 2) * NT * 32);
  int sr = l >> 2, sc = l & 3;

  float4v acc[4][NV];
  #pragma unroll
  for (int u = 0; u < 4; ++u)
    #pragma unroll
    for (int vv = 0; vv < NV; ++vv) acc[u][vv] = (float4v){0.f, 0.f, 0.f, 0.f};

  int quad = l >> 4, lo16 = l & 15;
  for (int kt = 0; kt < K; kt += 32) {
    __syncthreads();
    for (int i = 0; i < iters; ++i) {
      int row = i * 16 + sr;
      gload_lds16(src + (size_t)(rowbase + row) * K + kt + sc * 8,
                  dst + row * 32 + sc * 8);
    }
    __syncthreads();
    half8 ah[4], al[4], bh[NV], bl[NV];
    #pragma unroll
    for (int u = 0; u < 4; ++u) {
      int mrow = wm + u * 16 + lo16;
      ah[u] = *(const half8*)&lds[        (size_t)mrow * 32 + quad * 8];
      al[u] = *(const half8*)&lds[ 4096 + (size_t)mrow * 32 + quad * 8];
    }
    #pragma unroll
    for (int vv = 0; vv < NV; ++vv) {
      int nrow = wn + vv * 16 + lo16;
      bh[vv] = *(const half8*)&lds[8192           + (size_t)nrow * 32 + quad * 8];
      bl[vv] = *(const half8*)&lds[8192 + NT * 32 + (size_t)nrow * 32 + quad * 8];
    }
    #pragma unroll
    for (int u = 0; u < 4; ++u)
      #pragma unroll
      for (int vv = 0; vv < NV; ++vv) {
        acc[u][vv] = mfma16(ah[u], bh[vv], acc[u][vv]);
        acc[u][vv] = mfma16(ah[u], bl[vv], acc[u][vv]);
        acc[u][vv] = mfma16(al[u], bh[vv], acc[u][vv]);
      }
  }

  // epilogue: C row = m ((lane>>4)*4+reg), col = n (lane&15)
  #pragma unroll
  for (int u = 0; u < 4; ++u) {
    #pragma unroll
    for (int vv = 0; vv < NV; ++vv) {
      #pragma unroll
      for (int rg = 0; rg < 4; ++rg) {
        int row = m0 + wm + u * 16 + quad * 4 + rg;
        int col = n0 + wn + vv * 16 + lo16;
        float val = acc[u][vv][rg];
        if (MODE == 0) {
          int which = col >> 10, h = (col >> 6) & 15, dd = col & 63;
          int b = row >> 10, i = row & 1023;
          size_t e = ((size_t)(b * 16 + h) << 16) + ((size_t)i << 6) + dd;
          if (which == 2) { CV[e] = val; }
          else {
            HL sp = split2(val);
            if (which == 0) { QH[e] = sp.h; QL[e] = sp.l; }
            else            { KH[e] = sp.h; KL[e] = sp.l; }
          }
        } else {
          CO[(size_t)row * 1024 + col] = val + bias[col];
        }
      }
    }
  }
}

// ---------------- K3: fused MFMA sim + top-32 select + v gather-sum ---------
// 1024-thread blocks (16 waves share 66KB sim LDS -> 2 blocks/CU = 32
// waves/CU).  Wave w: 64-col MFMA strip; barrier; selects row w via ballot
// binary search (exact jax tie-break); gathers+sums 32 v rows.
__global__ __launch_bounds__(1024)
void attn_kernel(const _Float16* __restrict__ qh, const _Float16* __restrict__ ql,
                 const _Float16* __restrict__ kh, const _Float16* __restrict__ kl,
                 const float* __restrict__ vg, float* __restrict__ xsum) {
  __shared__ float simb[16][1028];   // stride 1028: writes land 2-way max (free)
  __shared__ int sel[16][32];
  // XCD swizzle: all 64 row-blocks of a head on one XCD (k planes fit L2)
  int g = blockIdx.x;
  int xcd = g & 7, slot = g >> 3;
  int bh = (slot >> 6) * 8 + xcd, grp = slot & 63;
  int tid = threadIdx.x, w = tid >> 6, l = tid & 63;
  int quad = l >> 4, lo16 = l & 15;
  size_t hb = (size_t)bh << 16;

  // A-frags: q rows grp*16..+15 (same for all 16 waves; L1 broadcast)
  const _Float16* qhp = qh + hb + ((size_t)(grp * 16 + lo16) << 6);
  const _Float16* qlp = ql + hb + ((size_t)(grp * 16 + lo16) << 6);
  half8 ah0 = *(const half8*)(qhp + quad * 8);
  half8 ah1 = *(const half8*)(qhp + 32 + quad * 8);
  half8 al0 = *(const half8*)(qlp + quad * 8);
  half8 al1 = *(const half8*)(qlp + 32 + quad * 8);

  const _Float16* khp = kh + hb;
  const _Float16* klp = kl + hb;
  int jbase = w * 64;

  #pragma unroll
  for (int tt = 0; tt < 4; ++tt) {
    size_t off = ((size_t)(jbase + tt * 16 + lo16) << 6) + quad * 8;
    half8 b0 = *(const half8*)(khp + off);
    half8 b1 = *(const half8*)(khp + off + 32);
    half8 c0 = *(const half8*)(klp + off);
    half8 c1 = *(const half8*)(klp + off + 32);
    float4v acc = (float4v){0.f, 0.f, 0.f, 0.f};
    acc = mfma16(ah0, b0, acc);
    acc = mfma16(ah0, c0, acc);
    acc = mfma16(al0, b0, acc);
    acc = mfma16(ah1, b1, acc);
    acc = mfma16(ah1, c1, acc);
    acc = mfma16(al1, b1, acc);
    int jc = jbase + tt * 16 + lo16;
    #pragma unroll
    for (int rg = 0; rg < 4; ++rg)
      simb[quad * 4 + rg][jc] = acc[rg];
  }
  __syncthreads();

  // wave w selects row w
  unsigned ku[16];
  #pragma unroll
  for (int s = 0; s < 16; ++s) ku[s] = fkey(simb[w][s * 64 + l]);

  // binary search for 32nd-largest key; early exit at exact count 32.
  // Exactness note: exit fires at the first bit where k32 and k33 differ,
  // so the non-exact path only runs on bit-exact fp32 ties (rare).
  unsigned cur = 0u;
  bool exact = false;
  for (int bit = 31; bit >= 0; --bit) {
    unsigned T = cur | (1u << bit);
    int c = 0;
    #pragma unroll
    for (int s = 0; s < 16; ++s) c += __popcll(__ballot(ku[s] >= T));
    if (c >= 32) {
      cur = T;
      if (c == 32) { exact = true; break; }
    }
  }

  int base = 0;
  if (exact) {
    // fast take: set is exactly {ku >= cur}; ascending-j compaction
    #pragma unroll
    for (int s = 0; s < 16; ++s) {
      bool take = ku[s] >= cur;
      unsigned long long mtk = __ballot(take);
      if (take) sel[w][base + mbcnt(mtk)] = s * 64 + l;
      base += __popcll(mtk);
    }
  } else {
    int gcnt = 0;
    #pragma unroll
    for (int s = 0; s < 16; ++s) gcnt += __popcll(__ballot(ku[s] > cur));
    int need = 32 - gcnt;   // ties taken lowest-j first (jax tie-break)
    int eqb = 0;
    #pragma unroll
    for (int s = 0; s < 16; ++s) {
      bool gt = ku[s] > cur;
      bool eq = ku[s] == cur;
      unsigned long long meq = __ballot(eq);
      int eqr = eqb + mbcnt(meq);
      bool take = gt || (eq && (eqr < need));
      unsigned long long mtk = __ballot(take);
      if (take) sel[w][base + mbcnt(mtk)] = s * 64 + l;
      base += __popcll(mtk);
      eqb  += __popcll(meq);
    }
  }

  const float* vb = vg + hb + l;       // hoisted: lane-fixed feature column
  float acc = 0.0f;
  #pragma unroll
  for (int s2 = 0; s2 < 32; ++s2) {
    int j = sel[w][s2];
    acc += vb[(size_t)j << 6];
  }
  xsum[hb + ((size_t)(grp * 16 + w) << 6) + l] = acc;
}

// ---------------- K4: global min/max reduce over xsum (256 blocks) ----------
__global__ __launch_bounds__(256)
void reduce_kernel(const float* __restrict__ xsum, int* __restrict__ minmax) {
  __shared__ float red[8];
  int tid = threadIdx.x, w = tid >> 6, l = tid & 63;
  const float4* p = (const float4*)xsum + (size_t)blockIdx.x * 4096 + tid;
  float mn = 3.4e38f, mx = -3.4e38f;
  #pragma unroll
  for (int i = 0; i < 16; ++i) {
    float4 v = p[(size_t)i * 256];
    mn = fminf(mn, fminf(fminf(v.x, v.y), fminf(v.z, v.w)));
    mx = fmaxf(mx, fmaxf(fmaxf(v.x, v.y), fmaxf(v.z, v.w)));
  }
  #pragma unroll
  for (int o = 32; o >= 1; o >>= 1) {
    mn = fminf(mn, __shfl_xor(mn, o, 64));
    mx = fmaxf(mx, __shfl_xor(mx, o, 64));
  }
  if (l == 0) { red[w*2] = mn; red[w*2+1] = mx; }
  __syncthreads();
  if (tid == 0) {
    mn = fminf(fminf(red[0], red[2]), fminf(red[4], red[6]));
    mx = fmaxf(fmaxf(red[1], red[3]), fmaxf(red[5], red[7]));
    atomicMin(minmax,     enc_i(mn));
    atomicMax(minmax + 1, enc_i(mx));
  }
}

// ---------------- K5: minmax-norm + exp + transpose -> f16 hi/lo ------------
__global__ __launch_bounds__(256)
void fin_kernel(const float* __restrict__ xsum, const int* __restrict__ minmax,
                _Float16* __restrict__ oh, _Float16* __restrict__ ol) {
  int idx = blockIdx.x * 256 + threadIdx.x;  // float4 index
  float mn = dec_i(minmax[0]);
  float mx = dec_i(minmax[1]);
  float inv = 1.0f / (mx - mn);
  float4 xv = ((const float4*)xsum)[idx];
  float o0 = expf((xv.x - mn) * inv);
  float o1 = expf((xv.y - mn) * inv);
  float o2 = expf((xv.z - mn) * inv);
  float o3 = expf((xv.w - mn) * inv);
  HL r0 = split2(o0), r1 = split2(o1), r2 = split2(o2), r3 = split2(o3);
  half4 hh = { r0.h, r1.h, r2.h, r3.h };
  half4 ll = { r0.l, r1.l, r2.l, r3.l };
  int e0 = idx << 2;
  int bh = e0 >> 16, i = (e0 >> 6) & 1023, dd = e0 & 63;
  int b = bh >> 4, h = bh & 15;
  size_t oe = ((size_t)(b * 1024 + i) << 10) + (h << 6) + dd;
  *(half4*)(oh + oe) = hh;
  *(half4*)(ol + oe) = ll;
}

// ---------------- launch ----------------
extern "C" void kernel_launch(void* const* d_in, const int* in_sizes, int n_in,
                              void* d_out, int out_size, void* d_ws, size_t ws_size,
                              hipStream_t stream) {
  const float* x     = (const float*)d_in[0];
  const float* gamma = (const float*)d_in[1];
  const float* beta  = (const float*)d_in[2];
  const float* w_qkv = (const float*)d_in[3];
  const float* w_out = (const float*)d_in[4];
  const float* b_out = (const float*)d_in[5];

  char* B = (char*)d_ws;
  const size_t MB = 1024ull * 1024ull;
  float*    v   = (float*)B;                        // 16 MB [bh][n][d]
  _Float16* qh  = (_Float16*)(B + 16*MB);           // 8 MB each plane
  _Float16* ql  = (_Float16*)(B + 24*MB);
  _Float16* kh  = (_Float16*)(B + 32*MB);
  _Float16* kl  = (_Float16*)(B + 40*MB);
  float*    xs  = (float*)(B + 48*MB);              // 16 MB (attn output)
  _Float16* xh  = (_Float16*)(B + 48*MB);           // LN planes (dead before xs)
  _Float16* xl  = (_Float16*)(B + 56*MB);
  _Float16* woh = (_Float16*)(B + 64*MB);           // 2 MB each
  _Float16* wol = (_Float16*)(B + 66*MB);
  int*   minmax = (int*)(B + 68*MB);
  _Float16* wqh = (_Float16*)(B + 69*MB);           // 6 MB each
  _Float16* wql = (_Float16*)(B + 75*MB);
  _Float16* oth = qh;                               // reuse q planes after attn
  _Float16* otl = ql;

  prep_kernel<<<8193, 256, 0, stream>>>(x, gamma, beta, xh, xl,
                                        w_qkv, w_out, wqh, wql, woh, wol,
                                        minmax);
  gemm_f16split<0, 128><<<dim3(24, 32), 256, 0, stream>>>(
      xh, xl, wqh, wql, nullptr, nullptr, qh, ql, kh, kl, v);
  attn_kernel<<<4096, 1024, 0, stream>>>(qh, ql, kh, kl, v, xs);
  reduce_kernel<<<256, 256, 0, stream>>>(xs, minmax);
  fin_kernel<<<4096, 256, 0, stream>>>(xs, minmax, oth, otl);
  gemm_f16split<1, 64><<<dim3(16, 32), 256, 0, stream>>>(
      oth, otl, woh, wol, b_out, (float*)d_out,
      nullptr, nullptr, nullptr, nullptr, nullptr);
}

// Round 13
// 407.409 us; speedup vs baseline: 1.1764x; 1.0202x over previous
//
#include <hip/hip_runtime.h>

// ProdAttention: LN -> QKV proj -> per-head top-32 of q.k^T (softmax monotone
// => select on raw sim) -> unweighted gather-sum of selected v rows -> global
// minmax-normalize + exp -> transpose -> output proj + bias.
// GEMM-shaped compute on MFMA with f16 hi/lo split (3 terms ~ fp32).
// R13: gather vectorized to float4 (8 VMEM/wave instead of 32) + 2-step
// shuffle reduce.  Single isolated change vs R12 (R10 bundled this with the
// prefilter regression; isolating the good part).

#define LN_EPS 1e-5f

using half8   = __attribute__((ext_vector_type(8))) _Float16;
using half4   = __attribute__((ext_vector_type(4))) _Float16;
using float4v = __attribute__((ext_vector_type(4))) float;

__device__ __forceinline__ void gload_lds16(const void* g, void* l) {
  __builtin_amdgcn_global_load_lds(
      (const __attribute__((address_space(1))) void*)g,
      (__attribute__((address_space(3))) void*)l, 16, 0, 0);
}
__device__ __forceinline__ float4v mfma16(half8 a, half8 b, float4v c) {
  return __builtin_amdgcn_mfma_f32_16x16x32_f16(a, b, c, 0, 0, 0);
}
struct HL { _Float16 h, l; };
__device__ __forceinline__ HL split2(float x) {
  _Float16 h = (_Float16)x;
  return { h, (_Float16)(x - (float)h) };
}
// rank of this lane within mask (count of set bits strictly below my lane)
__device__ __forceinline__ int mbcnt(unsigned long long m) {
  return __builtin_amdgcn_mbcnt_hi((unsigned)(m >> 32),
         __builtin_amdgcn_mbcnt_lo((unsigned)m, 0u));
}

// ---------------- order-preserving key helpers ----------------
__device__ __forceinline__ unsigned fkey(float f) {
  unsigned u = __float_as_uint(f);
  return ((int)u < 0) ? ~u : (u | 0x80000000u);
}
__device__ __forceinline__ int enc_i(float f) {
  int i = __float_as_int(f);
  return i >= 0 ? i : (i ^ 0x7fffffff);
}
__device__ __forceinline__ float dec_i(int e) {
  return __int_as_float(e >= 0 ? e : (e ^ 0x7fffffff));
}

// ---------------- K1: LN + weight-convert + minmax-init (fused) -------------
// blocks 0..4095: LN row; 4096..8191: weight cvt chunk; 8192: minmax init.
__global__ __launch_bounds__(256)
void prep_kernel(const float* __restrict__ x, const float* __restrict__ gamma,
                 const float* __restrict__ beta,
                 _Float16* __restrict__ xh, _Float16* __restrict__ xl,
                 const float* __restrict__ wqkv, const float* __restrict__ wout,
                 _Float16* __restrict__ wqh, _Float16* __restrict__ wql,
                 _Float16* __restrict__ woh, _Float16* __restrict__ wol,
                 int* __restrict__ minmax) {
  int blk = blockIdx.x, t = threadIdx.x;
  if (blk < 4096) {
    __shared__ float red[8];
    int row = blk;
    const float4* xr = (const float4*)(x + (size_t)row * 1024);
    float4 v = xr[t];
    float s  = v.x + v.y + v.z + v.w;
    float s2 = v.x*v.x + v.y*v.y + v.z*v.z + v.w*v.w;
    #pragma unroll
    for (int o = 32; o >= 1; o >>= 1) {
      s  += __shfl_xor(s,  o, 64);
      s2 += __shfl_xor(s2, o, 64);
    }
    int w = t >> 6, l = t & 63;
    if (l == 0) { red[w*2] = s; red[w*2+1] = s2; }
    __syncthreads();
    float S  = red[0] + red[2] + red[4] + red[6];
    float S2 = red[1] + red[3] + red[5] + red[7];
    float mu  = S * (1.0f/1024.0f);
    float var = S2 * (1.0f/1024.0f) - mu*mu;
    float r = rsqrtf(var + LN_EPS);
    float4 g  = ((const float4*)gamma)[t];
    float4 bb = ((const float4*)beta)[t];
    float o0 = (v.x - mu) * r * g.x + bb.x;
    float o1 = (v.y - mu) * r * g.y + bb.y;
    float o2 = (v.z - mu) * r * g.z + bb.z;
    float o3 = (v.w - mu) * r * g.w + bb.w;
    HL r0 = split2(o0), r1 = split2(o1), r2 = split2(o2), r3 = split2(o3);
    half4 hh = { r0.h, r1.h, r2.h, r3.h };
    half4 ll = { r0.l, r1.l, r2.l, r3.l };
    size_t e = (size_t)row * 1024 + t*4;
    *(half4*)(xh + e) = hh;
    *(half4*)(xl + e) = ll;
  } else if (blk < 8192) {
    size_t i4 = (size_t)(blk - 4096) * 256 + t;   // float4 index, 1M total
    const float* src; _Float16 *dh, *dl; size_t off;
    if (i4 < 786432) { src = wqkv; dh = wqh; dl = wql; off = i4; }
    else             { src = wout; dh = woh; dl = wol; off = i4 - 786432; }
    float4 v = ((const float4*)src)[off];
    HL r0 = split2(v.x), r1 = split2(v.y), r2 = split2(v.z), r3 = split2(v.w);
    half4 hh = { r0.h, r1.h, r2.h, r3.h };
    half4 ll = { r0.l, r1.l, r2.l, r3.l };
    ((half4*)dh)[off] = hh;
    ((half4*)dl)[off] = ll;
  } else if (t == 0) {
    minmax[0] = 0x7fffffff;
    minmax[1] = (int)0x80000000;
  }
}

// ---------------- K2/K6: f16-split MFMA NT GEMM, 128xNT tile ----------------
// C[m][n] = sum_k A[m][k]*B[n][k], A = Ah+Al, B = Bh+Bl (3 MFMA terms).
// MODE 0 (NT=128): scatter q,k -> f16 hi/lo planes [bh][n][d]; v fp32.
// MODE 1 (NT=64):  CO = acc + bias (fp32); 2 blocks/CU for latency hiding.
template<int MODE, int NT>
__global__ __launch_bounds__(256)
void gemm_f16split(const _Float16* __restrict__ Ah, const _Float16* __restrict__ Al,
                   const _Float16* __restrict__ Bh, const _Float16* __restrict__ Bl,
                   const float* __restrict__ bias, float* __restrict__ CO,
                   _Float16* __restrict__ QH, _Float16* __restrict__ QL,
                   _Float16* __restrict__ KH, _Float16* __restrict__ KL,
                   float* __restrict__ CV) {
  constexpr int NV = NT / 32;                     // n-tiles per wave
  __shared__ __align__(16) _Float16 lds[8192 + 2 * NT * 32];  // Ah|Al|Bh|Bl
  const int K = 1024;
  int tid = threadIdx.x, w = tid >> 6, l = tid & 63;
  int m0 = blockIdx.y * 128, n0 = blockIdx.x * NT;
  int wm = (w >> 1) * 64, wn = (w & 1) * (NT / 2);

  const _Float16* src = (w == 0) ? Ah : (w == 1) ? Al : (w == 2) ? Bh : Bl;
  int rowbase = (w < 2) ? m0 : n0;
  int iters   = (w < 2) ? 8 : NT / 16;
  _Float16* dst = lds + ((w < 2) ? (size_t)w * 4096
                                 : (size_t)8192 + (size_t)(w - 2) * NT * 32);
  int sr = l >> 2, sc = l & 3;

  float4v acc[4][NV];
  #pragma unroll
  for (int u = 0; u < 4; ++u)
    #pragma unroll
    for (int vv = 0; vv < NV; ++vv) acc[u][vv] = (float4v){0.f, 0.f, 0.f, 0.f};

  int quad = l >> 4, lo16 = l & 15;
  for (int kt = 0; kt < K; kt += 32) {
    __syncthreads();
    for (int i = 0; i < iters; ++i) {
      int row = i * 16 + sr;
      gload_lds16(src + (size_t)(rowbase + row) * K + kt + sc * 8,
                  dst + row * 32 + sc * 8);
    }
    __syncthreads();
    half8 ah[4], al[4], bh[NV], bl[NV];
    #pragma unroll
    for (int u = 0; u < 4; ++u) {
      int mrow = wm + u * 16 + lo16;
      ah[u] = *(const half8*)&lds[        (size_t)mrow * 32 + quad * 8];
      al[u] = *(const half8*)&lds[ 4096 + (size_t)mrow * 32 + quad * 8];
    }
    #pragma unroll
    for (int vv = 0; vv < NV; ++vv) {
      int nrow = wn + vv * 16 + lo16;
      bh[vv] = *(const half8*)&lds[8192           + (size_t)nrow * 32 + quad * 8];
      bl[vv] = *(const half8*)&lds[8192 + NT * 32 + (size_t)nrow * 32 + quad * 8];
    }
    #pragma unroll
    for (int u = 0; u < 4; ++u)
      #pragma unroll
      for (int vv = 0; vv < NV; ++vv) {
        acc[u][vv] = mfma16(ah[u], bh[vv], acc[u][vv]);
        acc[u][vv] = mfma16(ah[u], bl[vv], acc[u][vv]);
        acc[u][vv] = mfma16(al[u], bh[vv], acc[u][vv]);
      }
  }

  // epilogue: C row = m ((lane>>4)*4+reg), col = n (lane&15)
  #pragma unroll
  for (int u = 0; u < 4; ++u) {
    #pragma unroll
    for (int vv = 0; vv < NV; ++vv) {
      #pragma unroll
      for (int rg = 0; rg < 4; ++rg) {
        int row = m0 + wm + u * 16 + quad * 4 + rg;
        int col = n0 + wn + vv * 16 + lo16;
        float val = acc[u][vv][rg];
        if (MODE == 0) {
          int which = col >> 10, h = (col >> 6) & 15, dd = col & 63;
          int b = row >> 10, i = row & 1023;
          size_t e = ((size_t)(b * 16 + h) << 16) + ((size_t)i << 6) + dd;
          if (which == 2) { CV[e] = val; }
          else {
            HL sp = split2(val);
            if (which == 0) { QH[e] = sp.h; QL[e] = sp.l; }
            else            { KH[e] = sp.h; KL[e] = sp.l; }
          }
        } else {
          CO[(size_t)row * 1024 + col] = val + bias[col];
        }
      }
    }
  }
}

// ---------------- K3: fused MFMA sim + top-32 select + v gather-sum ---------
// 1024-thread blocks (16 waves share 66KB sim LDS -> 2 blocks/CU = 32
// waves/CU).  Wave w: 64-col MFMA strip; barrier; selects row w via ballot
// binary search (exact jax tie-break); float4 gather + shuffle reduce.
__global__ __launch_bounds__(1024)
void attn_kernel(const _Float16* __restrict__ qh, const _Float16* __restrict__ ql,
                 const _Float16* __restrict__ kh, const _Float16* __restrict__ kl,
                 const float* __restrict__ vg, float* __restrict__ xsum) {
  __shared__ float simb[16][1028];   // stride 1028: writes land 2-way max (free)
  __shared__ int sel[16][32];
  // XCD swizzle: all 64 row-blocks of a head on one XCD (k planes fit L2)
  int g = blockIdx.x;
  int xcd = g & 7, slot = g >> 3;
  int bh = (slot >> 6) * 8 + xcd, grp = slot & 63;
  int tid = threadIdx.x, w = tid >> 6, l = tid & 63;
  int quad = l >> 4, lo16 = l & 15;
  size_t hb = (size_t)bh << 16;

  // A-frags: q rows grp*16..+15 (same for all 16 waves; L1 broadcast)
  const _Float16* qhp = qh + hb + ((size_t)(grp * 16 + lo16) << 6);
  const _Float16* qlp = ql + hb + ((size_t)(grp * 16 + lo16) << 6);
  half8 ah0 = *(const half8*)(qhp + quad * 8);
  half8 ah1 = *(const half8*)(qhp + 32 + quad * 8);
  half8 al0 = *(const half8*)(qlp + quad * 8);
  half8 al1 = *(const half8*)(qlp + 32 + quad * 8);

  const _Float16* khp = kh + hb;
  const _Float16* klp = kl + hb;
  int jbase = w * 64;

  #pragma unroll
  for (int tt = 0; tt < 4; ++tt) {
    size_t off = ((size_t)(jbase + tt * 16 + lo16) << 6) + quad * 8;
    half8 b0 = *(const half8*)(khp + off);
    half8 b1 = *(const half8*)(khp + off + 32);
    half8 c0 = *(const half8*)(klp + off);
    half8 c1 = *(const half8*)(klp + off + 32);
    float4v acc = (float4v){0.f, 0.f, 0.f, 0.f};
    acc = mfma16(ah0, b0, acc);
    acc = mfma16(ah0, c0, acc);
    acc = mfma16(al0, b0, acc);
    acc = mfma16(ah1, b1, acc);
    acc = mfma16(ah1, c1, acc);
    acc = mfma16(al1, b1, acc);
    int jc = jbase + tt * 16 + lo16;
    #pragma unroll
    for (int rg = 0; rg < 4; ++rg)
      simb[quad * 4 + rg][jc] = acc[rg];
  }
  __syncthreads();

  // wave w selects row w
  unsigned ku[16];
  #pragma unroll
  for (int s = 0; s < 16; ++s) ku[s] = fkey(simb[w][s * 64 + l]);

  // binary search for 32nd-largest key; early exit at exact count 32.
  // Exit fires at the first bit where k32 and k33 differ, so the non-exact
  // path only runs on bit-exact fp32 ties (rare).
  unsigned cur = 0u;
  bool exact = false;
  for (int bit = 31; bit >= 0; --bit) {
    unsigned T = cur | (1u << bit);
    int c = 0;
    #pragma unroll
    for (int s = 0; s < 16; ++s) c += __popcll(__ballot(ku[s] >= T));
    if (c >= 32) {
      cur = T;
      if (c == 32) { exact = true; break; }
    }
  }

  int base = 0;
  if (exact) {
    // fast take: set is exactly {ku >= cur}; ascending-j compaction
    #pragma unroll
    for (int s = 0; s < 16; ++s) {
      bool take = ku[s] >= cur;
      unsigned long long mtk = __ballot(take);
      if (take) sel[w][base + mbcnt(mtk)] = s * 64 + l;
      base += __popcll(mtk);
    }
  } else {
    int gcnt = 0;
    #pragma unroll
    for (int s = 0; s < 16; ++s) gcnt += __popcll(__ballot(ku[s] > cur));
    int need = 32 - gcnt;   // ties taken lowest-j first (jax tie-break)
    int eqb = 0;
    #pragma unroll
    for (int s = 0; s < 16; ++s) {
      bool gt = ku[s] > cur;
      bool eq = ku[s] == cur;
      unsigned long long meq = __ballot(eq);
      int eqr = eqb + mbcnt(meq);
      bool take = gt || (eq && (eqr < need));
      unsigned long long mtk = __ballot(take);
      if (take) sel[w][base + mbcnt(mtk)] = s * 64 + l;
      base += __popcll(mtk);
      eqb  += __popcll(meq);
    }
  }

  // float4 gather: lane-group (l>>4) covers 8 of 32 rows, cols (l&15)*4..+3;
  // then 2-step shuffle reduce over the 4 groups; lanes 0-15 store float4.
  const float* vb = vg + hb;
  int lg = l >> 4, lc = (l & 15) * 4;
  float4 vacc = {0.f, 0.f, 0.f, 0.f};
  #pragma unroll
  for (int p = 0; p < 8; ++p) {
    int j = sel[w][p * 4 + lg];
    float4 t = *(const float4*)(vb + ((size_t)j << 6) + lc);
    vacc.x += t.x; vacc.y += t.y; vacc.z += t.z; vacc.w += t.w;
  }
  #pragma unroll
  for (int o = 32; o >= 16; o >>= 1) {
    vacc.x += __shfl_xor(vacc.x, o, 64);
    vacc.y += __shfl_xor(vacc.y, o, 64);
    vacc.z += __shfl_xor(vacc.z, o, 64);
    vacc.w += __shfl_xor(vacc.w, o, 64);
  }
  if (l < 16)
    *(float4*)(xsum + hb + ((size_t)(grp * 16 + w) << 6) + l * 4) = vacc;
}

// ---------------- K4: global min/max reduce over xsum (256 blocks) ----------
__global__ __launch_bounds__(256)
void reduce_kernel(const float* __restrict__ xsum, int* __restrict__ minmax) {
  __shared__ float red[8];
  int tid = threadIdx.x, w = tid >> 6, l = tid & 63;
  const float4* p = (const float4*)xsum + (size_t)blockIdx.x * 4096 + tid;
  float mn = 3.4e38f, mx = -3.4e38f;
  #pragma unroll
  for (int i = 0; i < 16; ++i) {
    float4 v = p[(size_t)i * 256];
    mn = fminf(mn, fminf(fminf(v.x, v.y), fminf(v.z, v.w)));
    mx = fmaxf(mx, fmaxf(fmaxf(v.x, v.y), fmaxf(v.z, v.w)));
  }
  #pragma unroll
  for (int o = 32; o >= 1; o >>= 1) {
    mn = fminf(mn, __shfl_xor(mn, o, 64));
    mx = fmaxf(mx, __shfl_xor(mx, o, 64));
  }
  if (l == 0) { red[w*2] = mn; red[w*2+1] = mx; }
  __syncthreads();
  if (tid == 0) {
    mn = fminf(fminf(red[0], red[2]), fminf(red[4], red[6]));
    mx = fmaxf(fmaxf(red[1], red[3]), fmaxf(red[5], red[7]));
    atomicMin(minmax,     enc_i(mn));
    atomicMax(minmax + 1, enc_i(mx));
  }
}

// ---------------- K5: minmax-norm + exp + transpose -> f16 hi/lo ------------
__global__ __launch_bounds__(256)
void fin_kernel(const float* __restrict__ xsum, const int* __restrict__ minmax,
                _Float16* __restrict__ oh, _Float16* __restrict__ ol) {
  int idx = blockIdx.x * 256 + threadIdx.x;  // float4 index
  float mn = dec_i(minmax[0]);
  float mx = dec_i(minmax[1]);
  float inv = 1.0f / (mx - mn);
  float4 xv = ((const float4*)xsum)[idx];
  float o0 = expf((xv.x - mn) * inv);
  float o1 = expf((xv.y - mn) * inv);
  float o2 = expf((xv.z - mn) * inv);
  float o3 = expf((xv.w - mn) * inv);
  HL r0 = split2(o0), r1 = split2(o1), r2 = split2(o2), r3 = split2(o3);
  half4 hh = { r0.h, r1.h, r2.h, r3.h };
  half4 ll = { r0.l, r1.l, r2.l, r3.l };
  int e0 = idx << 2;
  int bh = e0 >> 16, i = (e0 >> 6) & 1023, dd = e0 & 63;
  int b = bh >> 4, h = bh & 15;
  size_t oe = ((size_t)(b * 1024 + i) << 10) + (h << 6) + dd;
  *(half4*)(oh + oe) = hh;
  *(half4*)(ol + oe) = ll;
}

// ---------------- launch ----------------
extern "C" void kernel_launch(void* const* d_in, const int* in_sizes, int n_in,
                              void* d_out, int out_size, void* d_ws, size_t ws_size,
                              hipStream_t stream) {
  const float* x     = (const float*)d_in[0];
  const float* gamma = (const float*)d_in[1];
  const float* beta  = (const float*)d_in[2];
  const float* w_qkv = (const float*)d_in[3];
  const float* w_out = (const float*)d_in[4];
  const float* b_out = (const float*)d_in[5];

  char* B = (char*)d_ws;
  const size_t MB = 1024ull * 1024ull;
  float*    v   = (float*)B;                        // 16 MB [bh][n][d]
  _Float16* qh  = (_Float16*)(B + 16*MB);           // 8 MB each plane
  _Float16* ql  = (_Float16*)(B + 24*MB);
  _Float16* kh  = (_Float16*)(B + 32*MB);
  _Float16* kl  = (_Float16*)(B + 40*MB);
  float*    xs  = (float*)(B + 48*MB);              // 16 MB (attn output)
  _Float16* xh  = (_Float16*)(B + 48*MB);           // LN planes (dead before xs)
  _Float16* xl  = (_Float16*)(B + 56*MB);
  _Float16* woh = (_Float16*)(B + 64*MB);           // 2 MB each
  _Float16* wol = (_Float16*)(B + 66*MB);
  int*   minmax = (int*)(B + 68*MB);
  _Float16* wqh = (_Float16*)(B + 69*MB);           // 6 MB each
  _Float16* wql = (_Float16*)(B + 75*MB);
  _Float16* oth = qh;                               // reuse q planes after attn
  _Float16* otl = ql;

  prep_kernel<<<8193, 256, 0, stream>>>(x, gamma, beta, xh, xl,
                                        w_qkv, w_out, wqh, wql, woh, wol,
                                        minmax);
  gemm_f16split<0, 128><<<dim3(24, 32), 256, 0, stream>>>(
      xh, xl, wqh, wql, nullptr, nullptr, qh, ql, kh, kl, v);
  attn_kernel<<<4096, 1024, 0, stream>>>(qh, ql, kh, kl, v, xs);
  reduce_kernel<<<256, 256, 0, stream>>>(xs, minmax);
  fin_kernel<<<4096, 256, 0, stream>>>(xs, minmax, oth, otl);
  gemm_f16split<1, 64><<<dim3(16, 32), 256, 0, stream>>>(
      oth, otl, woh, wol, b_out, (float*)d_out,
      nullptr, nullptr, nullptr, nullptr, nullptr);
}

// Round 14
// 393.653 us; speedup vs baseline: 1.2175x; 1.0349x over previous
//
#include <hip/hip_runtime.h>

// ProdAttention: LN -> QKV proj -> per-head top-32 of q.k^T (softmax monotone
// => select on raw sim) -> unweighted gather-sum of selected v rows -> global
// minmax-normalize + exp -> transpose -> output proj + bias.
// QKV GEMM + sim on MFMA with f16 hi/lo split (3 terms ~ fp32; selection
// needs it).  R14: out-proj GEMM is single-term f16 (post-selection, error
// ~1e-3 vs 0.135 threshold); reduce_kernel deleted -- attn does block minmax
// + per-head atomic slots (64 lines, shallow serialization), fin reduces the
// 128 slots at block start.  5 dispatches (was 6).

#define LN_EPS 1e-5f

using half8   = __attribute__((ext_vector_type(8))) _Float16;
using half4   = __attribute__((ext_vector_type(4))) _Float16;
using float4v = __attribute__((ext_vector_type(4))) float;

__device__ __forceinline__ void gload_lds16(const void* g, void* l) {
  __builtin_amdgcn_global_load_lds(
      (const __attribute__((address_space(1))) void*)g,
      (__attribute__((address_space(3))) void*)l, 16, 0, 0);
}
__device__ __forceinline__ float4v mfma16(half8 a, half8 b, float4v c) {
  return __builtin_amdgcn_mfma_f32_16x16x32_f16(a, b, c, 0, 0, 0);
}
struct HL { _Float16 h, l; };
__device__ __forceinline__ HL split2(float x) {
  _Float16 h = (_Float16)x;
  return { h, (_Float16)(x - (float)h) };
}
// rank of this lane within mask (count of set bits strictly below my lane)
__device__ __forceinline__ int mbcnt(unsigned long long m) {
  return __builtin_amdgcn_mbcnt_hi((unsigned)(m >> 32),
         __builtin_amdgcn_mbcnt_lo((unsigned)m, 0u));
}

// ---------------- order-preserving key helpers ----------------
__device__ __forceinline__ unsigned fkey(float f) {
  unsigned u = __float_as_uint(f);
  return ((int)u < 0) ? ~u : (u | 0x80000000u);
}
__device__ __forceinline__ int enc_i(float f) {
  int i = __float_as_int(f);
  return i >= 0 ? i : (i ^ 0x7fffffff);
}
__device__ __forceinline__ float dec_i(int e) {
  return __int_as_float(e >= 0 ? e : (e ^ 0x7fffffff));
}

// ---------------- K1: LN + weight-convert + minmax-slot-init (fused) --------
// blocks 0..4095: LN row; 4096..8191: weight cvt chunk; 8192: slot init.
__global__ __launch_bounds__(256)
void prep_kernel(const float* __restrict__ x, const float* __restrict__ gamma,
                 const float* __restrict__ beta,
                 _Float16* __restrict__ xh, _Float16* __restrict__ xl,
                 const float* __restrict__ wqkv, const float* __restrict__ wout,
                 _Float16* __restrict__ wqh, _Float16* __restrict__ wql,
                 _Float16* __restrict__ woh,
                 int* __restrict__ pmin, int* __restrict__ pmax) {
  int blk = blockIdx.x, t = threadIdx.x;
  if (blk < 4096) {
    __shared__ float red[8];
    int row = blk;
    const float4* xr = (const float4*)(x + (size_t)row * 1024);
    float4 v = xr[t];
    float s  = v.x + v.y + v.z + v.w;
    float s2 = v.x*v.x + v.y*v.y + v.z*v.z + v.w*v.w;
    #pragma unroll
    for (int o = 32; o >= 1; o >>= 1) {
      s  += __shfl_xor(s,  o, 64);
      s2 += __shfl_xor(s2, o, 64);
    }
    int w = t >> 6, l = t & 63;
    if (l == 0) { red[w*2] = s; red[w*2+1] = s2; }
    __syncthreads();
    float S  = red[0] + red[2] + red[4] + red[6];
    float S2 = red[1] + red[3] + red[5] + red[7];
    float mu  = S * (1.0f/1024.0f);
    float var = S2 * (1.0f/1024.0f) - mu*mu;
    float r = rsqrtf(var + LN_EPS);
    float4 g  = ((const float4*)gamma)[t];
    float4 bb = ((const float4*)beta)[t];
    float o0 = (v.x - mu) * r * g.x + bb.x;
    float o1 = (v.y - mu) * r * g.y + bb.y;
    float o2 = (v.z - mu) * r * g.z + bb.z;
    float o3 = (v.w - mu) * r * g.w + bb.w;
    HL r0 = split2(o0), r1 = split2(o1), r2 = split2(o2), r3 = split2(o3);
    half4 hh = { r0.h, r1.h, r2.h, r3.h };
    half4 ll = { r0.l, r1.l, r2.l, r3.l };
    size_t e = (size_t)row * 1024 + t*4;
    *(half4*)(xh + e) = hh;
    *(half4*)(xl + e) = ll;
  } else if (blk < 8192) {
    size_t i4 = (size_t)(blk - 4096) * 256 + t;   // float4 index, 1M total
    if (i4 < 786432) {            // w_qkv -> hi/lo planes (3-term gemm)
      float4 v = ((const float4*)wqkv)[i4];
      HL r0 = split2(v.x), r1 = split2(v.y), r2 = split2(v.z), r3 = split2(v.w);
      half4 hh = { r0.h, r1.h, r2.h, r3.h };
      half4 ll = { r0.l, r1.l, r2.l, r3.l };
      ((half4*)wqh)[i4] = hh;
      ((half4*)wql)[i4] = ll;
    } else {                      // w_out -> single f16 plane (1-term gemm)
      size_t off = i4 - 786432;
      float4 v = ((const float4*)wout)[off];
      half4 hh = { (_Float16)v.x, (_Float16)v.y, (_Float16)v.z, (_Float16)v.w };
      ((half4*)woh)[off] = hh;
    }
  } else {
    if (t < 64)              pmin[t]      = 0x7fffffff;
    else if (t < 128)        pmax[t - 64] = (int)0x80000000;
  }
}

// ---------------- K2: f16-split MFMA NT GEMM, 128x128 tile (QKV) ------------
// C[m][n] = sum_k A[m][k]*B[n][k], A = Ah+Al, B = Bh+Bl (3 MFMA terms).
// Scatters q,k -> f16 hi/lo planes [bh][n][d]; v -> fp32 [bh][n][d].
__global__ __launch_bounds__(256)
void gemm_qkv(const _Float16* __restrict__ Ah, const _Float16* __restrict__ Al,
              const _Float16* __restrict__ Bh, const _Float16* __restrict__ Bl,
              _Float16* __restrict__ QH, _Float16* __restrict__ QL,
              _Float16* __restrict__ KH, _Float16* __restrict__ KL,
              float* __restrict__ CV) {
  __shared__ __align__(16) _Float16 lds[4 * 128 * 32];  // Ah | Al | Bh | Bl
  const int K = 1024;
  int tid = threadIdx.x, w = tid >> 6, l = tid & 63;
  int m0 = blockIdx.y * 128, n0 = blockIdx.x * 128;
  int wm = (w >> 1) * 64, wn = (w & 1) * 64;

  const _Float16* src = (w == 0) ? Ah : (w == 1) ? Al : (w == 2) ? Bh : Bl;
  int rowbase = (w < 2) ? m0 : n0;
  _Float16* dst = lds + (size_t)w * 4096;
  int sr = l >> 2, sc = l & 3;

  float4v acc[4][4];
  #pragma unroll
  for (int u = 0; u < 4; ++u)
    #pragma unroll
    for (int vv = 0; vv < 4; ++vv) acc[u][vv] = (float4v){0.f, 0.f, 0.f, 0.f};

  int quad = l >> 4, lo16 = l & 15;
  for (int kt = 0; kt < K; kt += 32) {
    __syncthreads();
    #pragma unroll
    for (int i = 0; i < 8; ++i) {
      int row = i * 16 + sr;
      gload_lds16(src + (size_t)(rowbase + row) * K + kt + sc * 8,
                  dst + row * 32 + sc * 8);
    }
    __syncthreads();
    half8 ah[4], al[4], bh[4], bl[4];
    #pragma unroll
    for (int u = 0; u < 4; ++u) {
      int mrow = wm + u * 16 + lo16;
      int nrow = wn + u * 16 + lo16;
      ah[u] = *(const half8*)&lds[        (size_t)mrow * 32 + quad * 8];
      al[u] = *(const half8*)&lds[ 4096 + (size_t)mrow * 32 + quad * 8];
      bh[u] = *(const half8*)&lds[ 8192 + (size_t)nrow * 32 + quad * 8];
      bl[u] = *(const half8*)&lds[12288 + (size_t)nrow * 32 + quad * 8];
    }
    #pragma unroll
    for (int u = 0; u < 4; ++u)
      #pragma unroll
      for (int vv = 0; vv < 4; ++vv) {
        acc[u][vv] = mfma16(ah[u], bh[vv], acc[u][vv]);
        acc[u][vv] = mfma16(ah[u], bl[vv], acc[u][vv]);
        acc[u][vv] = mfma16(al[u], bh[vv], acc[u][vv]);
      }
  }

  // epilogue: C row = m ((lane>>4)*4+reg), col = n (lane&15)
  #pragma unroll
  for (int u = 0; u < 4; ++u) {
    #pragma unroll
    for (int vv = 0; vv < 4; ++vv) {
      #pragma unroll
      for (int rg = 0; rg < 4; ++rg) {
        int row = m0 + wm + u * 16 + quad * 4 + rg;
        int col = n0 + wn + vv * 16 + lo16;
        float val = acc[u][vv][rg];
        int which = col >> 10, h = (col >> 6) & 15, dd = col & 63;
        int b = row >> 10, i = row & 1023;
        size_t e = ((size_t)(b * 16 + h) << 16) + ((size_t)i << 6) + dd;
        if (which == 2) { CV[e] = val; }
        else {
          HL sp = split2(val);
          if (which == 0) { QH[e] = sp.h; QL[e] = sp.l; }
          else            { KH[e] = sp.h; KL[e] = sp.l; }
        }
      }
    }
  }
}

// ---------------- K3: fused MFMA sim + top-32 select + v gather-sum ---------
// 1024-thread blocks (16 waves share 66KB sim LDS -> 2 blocks/CU = 32
// waves/CU).  Wave w: 64-col MFMA strip; barrier; selects row w via ballot
// binary search (exact jax tie-break); float4 gather + shuffle reduce.
// Ends with block minmax -> per-head atomic slot (64 slots: shallow chains).
__global__ __launch_bounds__(1024)
void attn_kernel(const _Float16* __restrict__ qh, const _Float16* __restrict__ ql,
                 const _Float16* __restrict__ kh, const _Float16* __restrict__ kl,
                 const float* __restrict__ vg, float* __restrict__ xsum,
                 int* __restrict__ pmin, int* __restrict__ pmax) {
  __shared__ float simb[16][1028];   // stride 1028: writes land 2-way max (free)
  __shared__ int sel[16][32];
  __shared__ float bmn[16], bmx[16];
  // XCD swizzle: all 64 row-blocks of a head on one XCD (k planes fit L2)
  int g = blockIdx.x;
  int xcd = g & 7, slot = g >> 3;
  int bh = (slot >> 6) * 8 + xcd, grp = slot & 63;
  int tid = threadIdx.x, w = tid >> 6, l = tid & 63;
  int quad = l >> 4, lo16 = l & 15;
  size_t hb = (size_t)bh << 16;

  // A-frags: q rows grp*16..+15 (same for all 16 waves; L1 broadcast)
  const _Float16* qhp = qh + hb + ((size_t)(grp * 16 + lo16) << 6);
  const _Float16* qlp = ql + hb + ((size_t)(grp * 16 + lo16) << 6);
  half8 ah0 = *(const half8*)(qhp + quad * 8);
  half8 ah1 = *(const half8*)(qhp + 32 + quad * 8);
  half8 al0 = *(const half8*)(qlp + quad * 8);
  half8 al1 = *(const half8*)(qlp + 32 + quad * 8);

  const _Float16* khp = kh + hb;
  const _Float16* klp = kl + hb;
  int jbase = w * 64;

  #pragma unroll
  for (int tt = 0; tt < 4; ++tt) {
    size_t off = ((size_t)(jbase + tt * 16 + lo16) << 6) + quad * 8;
    half8 b0 = *(const half8*)(khp + off);
    half8 b1 = *(const half8*)(khp + off + 32);
    half8 c0 = *(const half8*)(klp + off);
    half8 c1 = *(const half8*)(klp + off + 32);
    float4v acc = (float4v){0.f, 0.f, 0.f, 0.f};
    acc = mfma16(ah0, b0, acc);
    acc = mfma16(ah0, c0, acc);
    acc = mfma16(al0, b0, acc);
    acc = mfma16(ah1, b1, acc);
    acc = mfma16(ah1, c1, acc);
    acc = mfma16(al1, b1, acc);
    int jc = jbase + tt * 16 + lo16;
    #pragma unroll
    for (int rg = 0; rg < 4; ++rg)
      simb[quad * 4 + rg][jc] = acc[rg];
  }
  __syncthreads();

  // wave w selects row w
  unsigned ku[16];
  #pragma unroll
  for (int s = 0; s < 16; ++s) ku[s] = fkey(simb[w][s * 64 + l]);

  // binary search for 32nd-largest key; early exit at exact count 32.
  unsigned cur = 0u;
  bool exact = false;
  for (int bit = 31; bit >= 0; --bit) {
    unsigned T = cur | (1u << bit);
    int c = 0;
    #pragma unroll
    for (int s = 0; s < 16; ++s) c += __popcll(__ballot(ku[s] >= T));
    if (c >= 32) {
      cur = T;
      if (c == 32) { exact = true; break; }
    }
  }

  int base = 0;
  if (exact) {
    // fast take: set is exactly {ku >= cur}; ascending-j compaction
    #pragma unroll
    for (int s = 0; s < 16; ++s) {
      bool take = ku[s] >= cur;
      unsigned long long mtk = __ballot(take);
      if (take) sel[w][base + mbcnt(mtk)] = s * 64 + l;
      base += __popcll(mtk);
    }
  } else {
    int gcnt = 0;
    #pragma unroll
    for (int s = 0; s < 16; ++s) gcnt += __popcll(__ballot(ku[s] > cur));
    int need = 32 - gcnt;   // ties taken lowest-j first (jax tie-break)
    int eqb = 0;
    #pragma unroll
    for (int s = 0; s < 16; ++s) {
      bool gt = ku[s] > cur;
      bool eq = ku[s] == cur;
      unsigned long long meq = __ballot(eq);
      int eqr = eqb + mbcnt(meq);
      bool take = gt || (eq && (eqr < need));
      unsigned long long mtk = __ballot(take);
      if (take) sel[w][base + mbcnt(mtk)] = s * 64 + l;
      base += __popcll(mtk);
      eqb  += __popcll(meq);
    }
  }

  // float4 gather: lane-group (l>>4) covers 8 of 32 rows, cols (l&15)*4..+3;
  // 2-step shuffle reduce -> every lane holds the full sum for cols (l&15).
  const float* vb = vg + hb;
  int lg = l >> 4, lc = (l & 15) * 4;
  float4 vacc = {0.f, 0.f, 0.f, 0.f};
  #pragma unroll
  for (int p = 0; p < 8; ++p) {
    int j = sel[w][p * 4 + lg];
    float4 t = *(const float4*)(vb + ((size_t)j << 6) + lc);
    vacc.x += t.x; vacc.y += t.y; vacc.z += t.z; vacc.w += t.w;
  }
  #pragma unroll
  for (int o = 32; o >= 16; o >>= 1) {
    vacc.x += __shfl_xor(vacc.x, o, 64);
    vacc.y += __shfl_xor(vacc.y, o, 64);
    vacc.z += __shfl_xor(vacc.z, o, 64);
    vacc.w += __shfl_xor(vacc.w, o, 64);
  }
  if (l < 16)
    *(float4*)(xsum + hb + ((size_t)(grp * 16 + w) << 6) + l * 4) = vacc;

  // block min/max -> per-head atomic slot (2 atomics/block, 64-deep chains)
  float m4 = fminf(fminf(vacc.x, vacc.y), fminf(vacc.z, vacc.w));
  float M4 = fmaxf(fmaxf(vacc.x, vacc.y), fmaxf(vacc.z, vacc.w));
  #pragma unroll
  for (int o = 8; o >= 1; o >>= 1) {
    m4 = fminf(m4, __shfl_xor(m4, o, 64));
    M4 = fmaxf(M4, __shfl_xor(M4, o, 64));
  }
  if (l == 0) { bmn[w] = m4; bmx[w] = M4; }
  __syncthreads();
  if (w == 0 && l < 16) {
    float a = bmn[l], b2 = bmx[l];
    #pragma unroll
    for (int o = 8; o >= 1; o >>= 1) {
      a  = fminf(a,  __shfl_xor(a,  o, 64));
      b2 = fmaxf(b2, __shfl_xor(b2, o, 64));
    }
    if (l == 0) {
      atomicMin(pmin + bh, enc_i(a));
      atomicMax(pmax + bh, enc_i(b2));
    }
  }
}

// ---------------- K4: minmax-norm + exp + transpose -> f16 ------------------
// Reduces the 64 per-head minmax slots at block start (512 B, L2-broadcast).
__global__ __launch_bounds__(256)
void fin_kernel(const float* __restrict__ xsum, const int* __restrict__ pmin,
                const int* __restrict__ pmax, _Float16* __restrict__ oh) {
  __shared__ float mm[2];
  int tid = threadIdx.x;
  if (tid < 64) {
    float fa = dec_i(pmin[tid]);
    float fb = dec_i(pmax[tid]);
    #pragma unroll
    for (int o = 32; o >= 1; o >>= 1) {
      fa = fminf(fa, __shfl_xor(fa, o, 64));
      fb = fmaxf(fb, __shfl_xor(fb, o, 64));
    }
    if (tid == 0) { mm[0] = fa; mm[1] = fb; }
  }
  __syncthreads();
  float mn = mm[0];
  float inv = 1.0f / (mm[1] - mn);
  int idx = blockIdx.x * 256 + tid;          // float4 index
  float4 xv = ((const float4*)xsum)[idx];
  half4 hh = { (_Float16)expf((xv.x - mn) * inv),
               (_Float16)expf((xv.y - mn) * inv),
               (_Float16)expf((xv.z - mn) * inv),
               (_Float16)expf((xv.w - mn) * inv) };
  int e0 = idx << 2;
  int bh = e0 >> 16, i = (e0 >> 6) & 1023, dd = e0 & 63;
  int b = bh >> 4, h = bh & 15;
  size_t oe = ((size_t)(b * 1024 + i) << 10) + (h << 6) + dd;
  *(half4*)(oh + oe) = hh;
}

// ---------------- K5: single-term f16 out-proj GEMM, 128x64 tile ------------
// C[m][n] = sum_k A[m][k]*B[n][k] + bias[n].  A = exp outputs (all in [1,e]:
// f16 error ~1e-3 at C, post-selection => safe).  Concatenated-row staging:
// LDS rows 0..127 = A tile, 128..191 = B tile; each wave stages 48 rows.
__global__ __launch_bounds__(256)
void gemm_out(const _Float16* __restrict__ A, const _Float16* __restrict__ Bw,
              const float* __restrict__ bias, float* __restrict__ CO) {
  __shared__ __align__(16) _Float16 lds[192 * 32];
  const int K = 1024;
  int tid = threadIdx.x, w = tid >> 6, l = tid & 63;
  int m0 = blockIdx.y * 128, n0 = blockIdx.x * 64;
  int wm = (w >> 1) * 64, wn = (w & 1) * 32;
  int sr = l >> 2, sc = l & 3;
  int quad = l >> 4, lo16 = l & 15;

  float4v acc[4][2];
  #pragma unroll
  for (int u = 0; u < 4; ++u)
    #pragma unroll
    for (int vv = 0; vv < 2; ++vv) acc[u][vv] = (float4v){0.f, 0.f, 0.f, 0.f};

  for (int kt = 0; kt < K; kt += 32) {
    __syncthreads();
    #pragma unroll
    for (int i = 0; i < 3; ++i) {
      int row = w * 48 + i * 16 + sr;      // 0..191, each exactly once
      const _Float16* sp = (row < 128)
          ? A  + (size_t)(m0 + row) * K + kt + sc * 8
          : Bw + (size_t)(n0 + row - 128) * K + kt + sc * 8;
      gload_lds16(sp, lds + row * 32 + sc * 8);
    }
    __syncthreads();
    half8 af[4], bf[2];
    #pragma unroll
    for (int u = 0; u < 4; ++u)
      af[u] = *(const half8*)&lds[(size_t)(wm + u * 16 + lo16) * 32 + quad * 8];
    #pragma unroll
    for (int vv = 0; vv < 2; ++vv)
      bf[vv] = *(const half8*)&lds[(size_t)(128 + wn + vv * 16 + lo16) * 32
                                   + quad * 8];
    #pragma unroll
    for (int u = 0; u < 4; ++u)
      #pragma unroll
      for (int vv = 0; vv < 2; ++vv)
        acc[u][vv] = mfma16(af[u], bf[vv], acc[u][vv]);
  }

  #pragma unroll
  for (int u = 0; u < 4; ++u) {
    #pragma unroll
    for (int vv = 0; vv < 2; ++vv) {
      #pragma unroll
      for (int rg = 0; rg < 4; ++rg) {
        int row = m0 + wm + u * 16 + quad * 4 + rg;
        int col = n0 + wn + vv * 16 + lo16;
        CO[(size_t)row * 1024 + col] = acc[u][vv][rg] + bias[col];
      }
    }
  }
}

// ---------------- launch ----------------
extern "C" void kernel_launch(void* const* d_in, const int* in_sizes, int n_in,
                              void* d_out, int out_size, void* d_ws, size_t ws_size,
                              hipStream_t stream) {
  const float* x     = (const float*)d_in[0];
  const float* gamma = (const float*)d_in[1];
  const float* beta  = (const float*)d_in[2];
  const float* w_qkv = (const float*)d_in[3];
  const float* w_out = (const float*)d_in[4];
  const float* b_out = (const float*)d_in[5];

  char* B = (char*)d_ws;
  const size_t MB = 1024ull * 1024ull;
  float*    v   = (float*)B;                        // 16 MB [bh][n][d]
  _Float16* qh  = (_Float16*)(B + 16*MB);           // 8 MB each plane
  _Float16* ql  = (_Float16*)(B + 24*MB);
  _Float16* kh  = (_Float16*)(B + 32*MB);
  _Float16* kl  = (_Float16*)(B + 40*MB);
  float*    xs  = (float*)(B + 48*MB);              // 16 MB (attn output)
  _Float16* xh  = (_Float16*)(B + 48*MB);           // LN planes (dead before xs)
  _Float16* xl  = (_Float16*)(B + 56*MB);
  _Float16* woh = (_Float16*)(B + 64*MB);           // 2 MB (single plane)
  int*     pmin = (int*)(B + 66*MB);                // 64 slots
  int*     pmax = (int*)(B + 66*MB + 4096);         // 64 slots
  _Float16* wqh = (_Float16*)(B + 69*MB);           // 6 MB each
  _Float16* wql = (_Float16*)(B + 75*MB);
  _Float16* oth = qh;                               // reuse q plane after attn

  prep_kernel<<<8193, 256, 0, stream>>>(x, gamma, beta, xh, xl,
                                        w_qkv, w_out, wqh, wql, woh,
                                        pmin, pmax);
  gemm_qkv<<<dim3(24, 32), 256, 0, stream>>>(
      xh, xl, wqh, wql, qh, ql, kh, kl, v);
  attn_kernel<<<4096, 1024, 0, stream>>>(qh, ql, kh, kl, v, xs, pmin, pmax);
  fin_kernel<<<4096, 256, 0, stream>>>(xs, pmin, pmax, oth);
  gemm_out<<<dim3(16, 32), 256, 0, stream>>>(oth, woh, b_out, (float*)d_out);
}

// Round 15
// 386.061 us; speedup vs baseline: 1.2414x; 1.0197x over previous
//
#include <hip/hip_runtime.h>

// ProdAttention: LN -> QKV proj -> per-head top-32 of q.k^T (softmax monotone
// => select on raw sim) -> unweighted gather-sum of selected v rows -> global
// minmax-normalize + exp -> transpose -> output proj + bias.
// QKV GEMM + sim on MFMA with f16 hi/lo split (3 terms ~ fp32; selection
// needs it).  Out-proj single-term f16 (post-selection).
// R15: (a) gemm_qkv MFMA issue reordered term-major -- consecutive MFMAs hit
// different accumulators (same per-acc order => bit-identical); (b) attn
// k-frag double-buffer (one vmcnt exposure instead of four; +16 VGPR <= 64
// budget at 8 waves/SIMD).

#define LN_EPS 1e-5f

using half8   = __attribute__((ext_vector_type(8))) _Float16;
using half4   = __attribute__((ext_vector_type(4))) _Float16;
using float4v = __attribute__((ext_vector_type(4))) float;

__device__ __forceinline__ void gload_lds16(const void* g, void* l) {
  __builtin_amdgcn_global_load_lds(
      (const __attribute__((address_space(1))) void*)g,
      (__attribute__((address_space(3))) void*)l, 16, 0, 0);
}
__device__ __forceinline__ float4v mfma16(half8 a, half8 b, float4v c) {
  return __builtin_amdgcn_mfma_f32_16x16x32_f16(a, b, c, 0, 0, 0);
}
struct HL { _Float16 h, l; };
__device__ __forceinline__ HL split2(float x) {
  _Float16 h = (_Float16)x;
  return { h, (_Float16)(x - (float)h) };
}
// rank of this lane within mask (count of set bits strictly below my lane)
__device__ __forceinline__ int mbcnt(unsigned long long m) {
  return __builtin_amdgcn_mbcnt_hi((unsigned)(m >> 32),
         __builtin_amdgcn_mbcnt_lo((unsigned)m, 0u));
}

// ---------------- order-preserving key helpers ----------------
__device__ __forceinline__ unsigned fkey(float f) {
  unsigned u = __float_as_uint(f);
  return ((int)u < 0) ? ~u : (u | 0x80000000u);
}
__device__ __forceinline__ int enc_i(float f) {
  int i = __float_as_int(f);
  return i >= 0 ? i : (i ^ 0x7fffffff);
}
__device__ __forceinline__ float dec_i(int e) {
  return __int_as_float(e >= 0 ? e : (e ^ 0x7fffffff));
}

// ---------------- K1: LN + weight-convert + minmax-slot-init (fused) --------
// blocks 0..4095: LN row; 4096..8191: weight cvt chunk; 8192: slot init.
__global__ __launch_bounds__(256)
void prep_kernel(const float* __restrict__ x, const float* __restrict__ gamma,
                 const float* __restrict__ beta,
                 _Float16* __restrict__ xh, _Float16* __restrict__ xl,
                 const float* __restrict__ wqkv, const float* __restrict__ wout,
                 _Float16* __restrict__ wqh, _Float16* __restrict__ wql,
                 _Float16* __restrict__ woh,
                 int* __restrict__ pmin, int* __restrict__ pmax) {
  int blk = blockIdx.x, t = threadIdx.x;
  if (blk < 4096) {
    __shared__ float red[8];
    int row = blk;
    const float4* xr = (const float4*)(x + (size_t)row * 1024);
    float4 v = xr[t];
    float s  = v.x + v.y + v.z + v.w;
    float s2 = v.x*v.x + v.y*v.y + v.z*v.z + v.w*v.w;
    #pragma unroll
    for (int o = 32; o >= 1; o >>= 1) {
      s  += __shfl_xor(s,  o, 64);
      s2 += __shfl_xor(s2, o, 64);
    }
    int w = t >> 6, l = t & 63;
    if (l == 0) { red[w*2] = s; red[w*2+1] = s2; }
    __syncthreads();
    float S  = red[0] + red[2] + red[4] + red[6];
    float S2 = red[1] + red[3] + red[5] + red[7];
    float mu  = S * (1.0f/1024.0f);
    float var = S2 * (1.0f/1024.0f) - mu*mu;
    float r = rsqrtf(var + LN_EPS);
    float4 g  = ((const float4*)gamma)[t];
    float4 bb = ((const float4*)beta)[t];
    float o0 = (v.x - mu) * r * g.x + bb.x;
    float o1 = (v.y - mu) * r * g.y + bb.y;
    float o2 = (v.z - mu) * r * g.z + bb.z;
    float o3 = (v.w - mu) * r * g.w + bb.w;
    HL r0 = split2(o0), r1 = split2(o1), r2 = split2(o2), r3 = split2(o3);
    half4 hh = { r0.h, r1.h, r2.h, r3.h };
    half4 ll = { r0.l, r1.l, r2.l, r3.l };
    size_t e = (size_t)row * 1024 + t*4;
    *(half4*)(xh + e) = hh;
    *(half4*)(xl + e) = ll;
  } else if (blk < 8192) {
    size_t i4 = (size_t)(blk - 4096) * 256 + t;   // float4 index, 1M total
    if (i4 < 786432) {            // w_qkv -> hi/lo planes (3-term gemm)
      float4 v = ((const float4*)wqkv)[i4];
      HL r0 = split2(v.x), r1 = split2(v.y), r2 = split2(v.z), r3 = split2(v.w);
      half4 hh = { r0.h, r1.h, r2.h, r3.h };
      half4 ll = { r0.l, r1.l, r2.l, r3.l };
      ((half4*)wqh)[i4] = hh;
      ((half4*)wql)[i4] = ll;
    } else {                      // w_out -> single f16 plane (1-term gemm)
      size_t off = i4 - 786432;
      float4 v = ((const float4*)wout)[off];
      half4 hh = { (_Float16)v.x, (_Float16)v.y, (_Float16)v.z, (_Float16)v.w };
      ((half4*)woh)[off] = hh;
    }
  } else {
    if (t < 64)              pmin[t]      = 0x7fffffff;
    else if (t < 128)        pmax[t - 64] = (int)0x80000000;
  }
}

// ---------------- K2: f16-split MFMA NT GEMM, 128x128 tile (QKV) ------------
// C[m][n] = sum_k A[m][k]*B[n][k], A = Ah+Al, B = Bh+Bl (3 MFMA terms,
// issued term-major so consecutive MFMAs hit independent accumulators).
// Scatters q,k -> f16 hi/lo planes [bh][n][d]; v -> fp32 [bh][n][d].
__global__ __launch_bounds__(256)
void gemm_qkv(const _Float16* __restrict__ Ah, const _Float16* __restrict__ Al,
              const _Float16* __restrict__ Bh, const _Float16* __restrict__ Bl,
              _Float16* __restrict__ QH, _Float16* __restrict__ QL,
              _Float16* __restrict__ KH, _Float16* __restrict__ KL,
              float* __restrict__ CV) {
  __shared__ __align__(16) _Float16 lds[4 * 128 * 32];  // Ah | Al | Bh | Bl
  const int K = 1024;
  int tid = threadIdx.x, w = tid >> 6, l = tid & 63;
  int m0 = blockIdx.y * 128, n0 = blockIdx.x * 128;
  int wm = (w >> 1) * 64, wn = (w & 1) * 64;

  const _Float16* src = (w == 0) ? Ah : (w == 1) ? Al : (w == 2) ? Bh : Bl;
  int rowbase = (w < 2) ? m0 : n0;
  _Float16* dst = lds + (size_t)w * 4096;
  int sr = l >> 2, sc = l & 3;

  float4v acc[4][4];
  #pragma unroll
  for (int u = 0; u < 4; ++u)
    #pragma unroll
    for (int vv = 0; vv < 4; ++vv) acc[u][vv] = (float4v){0.f, 0.f, 0.f, 0.f};

  int quad = l >> 4, lo16 = l & 15;
  for (int kt = 0; kt < K; kt += 32) {
    __syncthreads();
    #pragma unroll
    for (int i = 0; i < 8; ++i) {
      int row = i * 16 + sr;
      gload_lds16(src + (size_t)(rowbase + row) * K + kt + sc * 8,
                  dst + row * 32 + sc * 8);
    }
    __syncthreads();
    half8 ah[4], al[4], bh[4], bl[4];
    #pragma unroll
    for (int u = 0; u < 4; ++u) {
      int mrow = wm + u * 16 + lo16;
      int nrow = wn + u * 16 + lo16;
      ah[u] = *(const half8*)&lds[        (size_t)mrow * 32 + quad * 8];
      al[u] = *(const half8*)&lds[ 4096 + (size_t)mrow * 32 + quad * 8];
      bh[u] = *(const half8*)&lds[ 8192 + (size_t)nrow * 32 + quad * 8];
      bl[u] = *(const half8*)&lds[12288 + (size_t)nrow * 32 + quad * 8];
    }
    // term-major issue: 16 independent accumulators between dependent pairs
    #pragma unroll
    for (int u = 0; u < 4; ++u)
      #pragma unroll
      for (int vv = 0; vv < 4; ++vv)
        acc[u][vv] = mfma16(ah[u], bh[vv], acc[u][vv]);
    #pragma unroll
    for (int u = 0; u < 4; ++u)
      #pragma unroll
      for (int vv = 0; vv < 4; ++vv)
        acc[u][vv] = mfma16(ah[u], bl[vv], acc[u][vv]);
    #pragma unroll
    for (int u = 0; u < 4; ++u)
      #pragma unroll
      for (int vv = 0; vv < 4; ++vv)
        acc[u][vv] = mfma16(al[u], bh[vv], acc[u][vv]);
  }

  // epilogue: C row = m ((lane>>4)*4+reg), col = n (lane&15)
  #pragma unroll
  for (int u = 0; u < 4; ++u) {
    #pragma unroll
    for (int vv = 0; vv < 4; ++vv) {
      #pragma unroll
      for (int rg = 0; rg < 4; ++rg) {
        int row = m0 + wm + u * 16 + quad * 4 + rg;
        int col = n0 + wn + vv * 16 + lo16;
        float val = acc[u][vv][rg];
        int which = col >> 10, h = (col >> 6) & 15, dd = col & 63;
        int b = row >> 10, i = row & 1023;
        size_t e = ((size_t)(b * 16 + h) << 16) + ((size_t)i << 6) + dd;
        if (which == 2) { CV[e] = val; }
        else {
          HL sp = split2(val);
          if (which == 0) { QH[e] = sp.h; QL[e] = sp.l; }
          else            { KH[e] = sp.h; KL[e] = sp.l; }
        }
      }
    }
  }
}

// ---------------- K3: fused MFMA sim + top-32 select + v gather-sum ---------
// 1024-thread blocks (16 waves share 66KB sim LDS -> 2 blocks/CU = 32
// waves/CU).  Wave w: 64-col MFMA strip (k-frags double-buffered: one vmcnt
// exposure); barrier; selects row w via ballot binary search (exact jax
// tie-break); float4 gather + shuffle reduce; per-head minmax atomic slots.
__global__ __launch_bounds__(1024)
void attn_kernel(const _Float16* __restrict__ qh, const _Float16* __restrict__ ql,
                 const _Float16* __restrict__ kh, const _Float16* __restrict__ kl,
                 const float* __restrict__ vg, float* __restrict__ xsum,
                 int* __restrict__ pmin, int* __restrict__ pmax) {
  __shared__ float simb[16][1028];   // stride 1028: writes land 2-way max (free)
  __shared__ int sel[16][32];
  __shared__ float bmn[16], bmx[16];
  // XCD swizzle: all 64 row-blocks of a head on one XCD (k planes fit L2)
  int g = blockIdx.x;
  int xcd = g & 7, slot = g >> 3;
  int bh = (slot >> 6) * 8 + xcd, grp = slot & 63;
  int tid = threadIdx.x, w = tid >> 6, l = tid & 63;
  int quad = l >> 4, lo16 = l & 15;
  size_t hb = (size_t)bh << 16;

  // A-frags: q rows grp*16..+15 (same for all 16 waves; L1 broadcast)
  const _Float16* qhp = qh + hb + ((size_t)(grp * 16 + lo16) << 6);
  const _Float16* qlp = ql + hb + ((size_t)(grp * 16 + lo16) << 6);
  half8 ah0 = *(const half8*)(qhp + quad * 8);
  half8 ah1 = *(const half8*)(qhp + 32 + quad * 8);
  half8 al0 = *(const half8*)(qlp + quad * 8);
  half8 al1 = *(const half8*)(qlp + 32 + quad * 8);

  const _Float16* khp = kh + hb;
  const _Float16* klp = kl + hb;
  int jbase = w * 64;

  // double-buffered k-frag loads: prefetch tile tt+1 while computing tt
  half8 b0, b1, c0, c1, d0, d1, e0, e1;
  {
    size_t off = ((size_t)(jbase + lo16) << 6) + quad * 8;
    b0 = *(const half8*)(khp + off);
    b1 = *(const half8*)(khp + off + 32);
    c0 = *(const half8*)(klp + off);
    c1 = *(const half8*)(klp + off + 32);
  }
  #pragma unroll
  for (int tt = 0; tt < 4; ++tt) {
    if (tt < 3) {
      size_t off = ((size_t)(jbase + (tt + 1) * 16 + lo16) << 6) + quad * 8;
      d0 = *(const half8*)(khp + off);
      d1 = *(const half8*)(khp + off + 32);
      e0 = *(const half8*)(klp + off);
      e1 = *(const half8*)(klp + off + 32);
    }
    float4v acc = (float4v){0.f, 0.f, 0.f, 0.f};
    acc = mfma16(ah0, b0, acc);
    acc = mfma16(ah0, c0, acc);
    acc = mfma16(al0, b0, acc);
    acc = mfma16(ah1, b1, acc);
    acc = mfma16(ah1, c1, acc);
    acc = mfma16(al1, b1, acc);
    int jc = jbase + tt * 16 + lo16;
    #pragma unroll
    for (int rg = 0; rg < 4; ++rg)
      simb[quad * 4 + rg][jc] = acc[rg];
    b0 = d0; b1 = d1; c0 = e0; c1 = e1;
  }
  __syncthreads();

  // wave w selects row w
  unsigned ku[16];
  #pragma unroll
  for (int s = 0; s < 16; ++s) ku[s] = fkey(simb[w][s * 64 + l]);

  // binary search for 32nd-largest key; early exit at exact count 32.
  unsigned cur = 0u;
  bool exact = false;
  for (int bit = 31; bit >= 0; --bit) {
    unsigned T = cur | (1u << bit);
    int c = 0;
    #pragma unroll
    for (int s = 0; s < 16; ++s) c += __popcll(__ballot(ku[s] >= T));
    if (c >= 32) {
      cur = T;
      if (c == 32) { exact = true; break; }
    }
  }

  int base = 0;
  if (exact) {
    // fast take: set is exactly {ku >= cur}; ascending-j compaction
    #pragma unroll
    for (int s = 0; s < 16; ++s) {
      bool take = ku[s] >= cur;
      unsigned long long mtk = __ballot(take);
      if (take) sel[w][base + mbcnt(mtk)] = s * 64 + l;
      base += __popcll(mtk);
    }
  } else {
    int gcnt = 0;
    #pragma unroll
    for (int s = 0; s < 16; ++s) gcnt += __popcll(__ballot(ku[s] > cur));
    int need = 32 - gcnt;   // ties taken lowest-j first (jax tie-break)
    int eqb = 0;
    #pragma unroll
    for (int s = 0; s < 16; ++s) {
      bool gt = ku[s] > cur;
      bool eq = ku[s] == cur;
      unsigned long long meq = __ballot(eq);
      int eqr = eqb + mbcnt(meq);
      bool take = gt || (eq && (eqr < need));
      unsigned long long mtk = __ballot(take);
      if (take) sel[w][base + mbcnt(mtk)] = s * 64 + l;
      base += __popcll(mtk);
      eqb  += __popcll(meq);
    }
  }

  // float4 gather: lane-group (l>>4) covers 8 of 32 rows, cols (l&15)*4..+3;
  // 2-step shuffle reduce -> every lane holds the full sum for cols (l&15).
  const float* vb = vg + hb;
  int lg = l >> 4, lc = (l & 15) * 4;
  float4 vacc = {0.f, 0.f, 0.f, 0.f};
  #pragma unroll
  for (int p = 0; p < 8; ++p) {
    int j = sel[w][p * 4 + lg];
    float4 t = *(const float4*)(vb + ((size_t)j << 6) + lc);
    vacc.x += t.x; vacc.y += t.y; vacc.z += t.z; vacc.w += t.w;
  }
  #pragma unroll
  for (int o = 32; o >= 16; o >>= 1) {
    vacc.x += __shfl_xor(vacc.x, o, 64);
    vacc.y += __shfl_xor(vacc.y, o, 64);
    vacc.z += __shfl_xor(vacc.z, o, 64);
    vacc.w += __shfl_xor(vacc.w, o, 64);
  }
  if (l < 16)
    *(float4*)(xsum + hb + ((size_t)(grp * 16 + w) << 6) + l * 4) = vacc;

  // block min/max -> per-head atomic slot (2 atomics/block, 64-deep chains)
  float m4 = fminf(fminf(vacc.x, vacc.y), fminf(vacc.z, vacc.w));
  float M4 = fmaxf(fmaxf(vacc.x, vacc.y), fmaxf(vacc.z, vacc.w));
  #pragma unroll
  for (int o = 8; o >= 1; o >>= 1) {
    m4 = fminf(m4, __shfl_xor(m4, o, 64));
    M4 = fmaxf(M4, __shfl_xor(M4, o, 64));
  }
  if (l == 0) { bmn[w] = m4; bmx[w] = M4; }
  __syncthreads();
  if (w == 0 && l < 16) {
    float a = bmn[l], b2 = bmx[l];
    #pragma unroll
    for (int o = 8; o >= 1; o >>= 1) {
      a  = fminf(a,  __shfl_xor(a,  o, 64));
      b2 = fmaxf(b2, __shfl_xor(b2, o, 64));
    }
    if (l == 0) {
      atomicMin(pmin + bh, enc_i(a));
      atomicMax(pmax + bh, enc_i(b2));
    }
  }
}

// ---------------- K4: minmax-norm + exp + transpose -> f16 ------------------
// Reduces the 64 per-head minmax slots at block start (512 B, L2-broadcast).
__global__ __launch_bounds__(256)
void fin_kernel(const float* __restrict__ xsum, const int* __restrict__ pmin,
                const int* __restrict__ pmax, _Float16* __restrict__ oh) {
  __shared__ float mm[2];
  int tid = threadIdx.x;
  if (tid < 64) {
    float fa = dec_i(pmin[tid]);
    float fb = dec_i(pmax[tid]);
    #pragma unroll
    for (int o = 32; o >= 1; o >>= 1) {
      fa = fminf(fa, __shfl_xor(fa, o, 64));
      fb = fmaxf(fb, __shfl_xor(fb, o, 64));
    }
    if (tid == 0) { mm[0] = fa; mm[1] = fb; }
  }
  __syncthreads();
  float mn = mm[0];
  float inv = 1.0f / (mm[1] - mn);
  int idx = blockIdx.x * 256 + tid;          // float4 index
  float4 xv = ((const float4*)xsum)[idx];
  half4 hh = { (_Float16)expf((xv.x - mn) * inv),
               (_Float16)expf((xv.y - mn) * inv),
               (_Float16)expf((xv.z - mn) * inv),
               (_Float16)expf((xv.w - mn) * inv) };
  int e0 = idx << 2;
  int bh = e0 >> 16, i = (e0 >> 6) & 1023, dd = e0 & 63;
  int b = bh >> 4, h = bh & 15;
  size_t oe = ((size_t)(b * 1024 + i) << 10) + (h << 6) + dd;
  *(half4*)(oh + oe) = hh;
}

// ---------------- K5: single-term f16 out-proj GEMM, 128x64 tile ------------
// C[m][n] = sum_k A[m][k]*B[n][k] + bias[n].  A = exp outputs in [1,e]
// (f16 error ~1e-3 at C, post-selection => safe).
__global__ __launch_bounds__(256)
void gemm_out(const _Float16* __restrict__ A, const _Float16* __restrict__ Bw,
              const float* __restrict__ bias, float* __restrict__ CO) {
  __shared__ __align__(16) _Float16 lds[192 * 32];
  const int K = 1024;
  int tid = threadIdx.x, w = tid >> 6, l = tid & 63;
  int m0 = blockIdx.y * 128, n0 = blockIdx.x * 64;
  int wm = (w >> 1) * 64, wn = (w & 1) * 32;
  int sr = l >> 2, sc = l & 3;
  int quad = l >> 4, lo16 = l & 15;

  float4v acc[4][2];
  #pragma unroll
  for (int u = 0; u < 4; ++u)
    #pragma unroll
    for (int vv = 0; vv < 2; ++vv) acc[u][vv] = (float4v){0.f, 0.f, 0.f, 0.f};

  for (int kt = 0; kt < K; kt += 32) {
    __syncthreads();
    #pragma unroll
    for (int i = 0; i < 3; ++i) {
      int row = w * 48 + i * 16 + sr;      // 0..191, each exactly once
      const _Float16* sp = (row < 128)
          ? A  + (size_t)(m0 + row) * K + kt + sc * 8
          : Bw + (size_t)(n0 + row - 128) * K + kt + sc * 8;
      gload_lds16(sp, lds + row * 32 + sc * 8);
    }
    __syncthreads();
    half8 af[4], bf[2];
    #pragma unroll
    for (int u = 0; u < 4; ++u)
      af[u] = *(const half8*)&lds[(size_t)(wm + u * 16 + lo16) * 32 + quad * 8];
    #pragma unroll
    for (int vv = 0; vv < 2; ++vv)
      bf[vv] = *(const half8*)&lds[(size_t)(128 + wn + vv * 16 + lo16) * 32
                                   + quad * 8];
    #pragma unroll
    for (int u = 0; u < 4; ++u)
      #pragma unroll
      for (int vv = 0; vv < 2; ++vv)
        acc[u][vv] = mfma16(af[u], bf[vv], acc[u][vv]);
  }

  #pragma unroll
  for (int u = 0; u < 4; ++u) {
    #pragma unroll
    for (int vv = 0; vv < 2; ++vv) {
      #pragma unroll
      for (int rg = 0; rg < 4; ++rg) {
        int row = m0 + wm + u * 16 + quad * 4 + rg;
        int col = n0 + wn + vv * 16 + lo16;
        CO[(size_t)row * 1024 + col] = acc[u][vv][rg] + bias[col];
      }
    }
  }
}

// ---------------- launch ----------------
extern "C" void kernel_launch(void* const* d_in, const int* in_sizes, int n_in,
                              void* d_out, int out_size, void* d_ws, size_t ws_size,
                              hipStream_t stream) {
  const float* x     = (const float*)d_in[0];
  const float* gamma = (const float*)d_in[1];
  const float* beta  = (const float*)d_in[2];
  const float* w_qkv = (const float*)d_in[3];
  const float* w_out = (const float*)d_in[4];
  const float* b_out = (const float*)d_in[5];

  char* B = (char*)d_ws;
  const size_t MB = 1024ull * 1024ull;
  float*    v   = (float*)B;                        // 16 MB [bh][n][d]
  _Float16* qh  = (_Float16*)(B + 16*MB);           // 8 MB each plane
  _Float16* ql  = (_Float16*)(B + 24*MB);
  _Float16* kh  = (_Float16*)(B + 32*MB);
  _Float16* kl  = (_Float16*)(B + 40*MB);
  float*    xs  = (float*)(B + 48*MB);              // 16 MB (attn output)
  _Float16* xh  = (_Float16*)(B + 48*MB);           // LN planes (dead before xs)
  _Float16* xl  = (_Float16*)(B + 56*MB);
  _Float16* woh = (_Float16*)(B + 64*MB);           // 2 MB (single plane)
  int*     pmin = (int*)(B + 66*MB);                // 64 slots
  int*     pmax = (int*)(B + 66*MB + 4096);         // 64 slots
  _Float16* wqh = (_Float16*)(B + 69*MB);           // 6 MB each
  _Float16* wql = (_Float16*)(B + 75*MB);
  _Float16* oth = qh;                               // reuse q plane after attn

  prep_kernel<<<8193, 256, 0, stream>>>(x, gamma, beta, xh, xl,
                                        w_qkv, w_out, wqh, wql, woh,
                                        pmin, pmax);
  gemm_qkv<<<dim3(24, 32), 256, 0, stream>>>(
      xh, xl, wqh, wql, qh, ql, kh, kl, v);
  attn_kernel<<<4096, 1024, 0, stream>>>(qh, ql, kh, kl, v, xs, pmin, pmax);
  fin_kernel<<<4096, 256, 0, stream>>>(xs, pmin, pmax, oth);
  gemm_out<<<dim3(16, 32), 256, 0, stream>>>(oth, woh, b_out, (float*)d_out);
}